// Round 14
// baseline (1057.124 us; speedup 1.0000x reference)
//
#include <hip/hip_runtime.h>
#include <math.h>

// ---------------------------------------------------------------------------
// S2ConvNet_deep: 7 spectral conv layers (1 S2 + 6 SO3) + SO3-integrate + MLP.
// All constant tables computed on-device every call (graph-capture safe).
// R1..R14: see git history (z-GEMM, fused synth, Hermitian halving, fft2).
// R15..R20: synth60 gather evolution (in-place P2, LDS 14.9KB, 180us).
// R21/R22: synth60 phase-1 pipeline; fp32 wigner; integrate pre-kernel (1369).
// R23: z_so3_gemm split-K + big-l-first -> 1040us.
// R24: g_build60 (j-batched coalesced G-build) + synth60b -> 1020us.
// R25/R26: wigner_jm_kernel (j-as-lane) -> wigner off the top-5.
// R27: radix-2 fold in both fft2 passes -> 1015us. New top: synth60b @72.5us
//      (VALU 65%, not BW-bound).
// R28: phase-4 loop interchange (m-outer, a-inner) in synth60b and synth30:
//      the sP1[m*N+g] LDS read is shared across the 4 (resp 2) a-values
//      (232 -> 145 LDS reads/thread, ~25% fewer VALU ops). Safe now because
//      synth60b has no phase-1 register state (R19's VGPR blowup combined
//      m-outer WITH cross-barrier pacc + phase-1 arrays; both are gone).
// ---------------------------------------------------------------------------

#define DFT_LDS 3712   // float2 slots for DFT staging (29.7 KB)

__host__ __device__ inline long long SF(int l) { return (long long)l * (4LL*l*l - 1) / 3; }
__device__ inline int imod(int a, int n) { int r = a % n; return r < 0 ? r + n : r; }

// ---------------- Wigner small-d, j-major segments (fp32 core) --------------
struct WigCfg {
    int nseg;
    int nblk[16];
    int off[16];
    int b_out[16];
    int colmode[16];
    int jmaj[16];
    int nb[16];
    double beta0[16];
    double bstep[16];
};

__global__ void wigner_all_kernel(float* __restrict__ ws, WigCfg cfg)
{
    __shared__ float lf[128];
    for (int t = threadIdx.x; t < 128; t += blockDim.x)
        lf[t] = (float)lgamma((double)t + 1.0);
    __syncthreads();

    int b = blockIdx.x, s = 0;
    while (b >= cfg.nblk[s]) { b -= cfg.nblk[s]; s++; }
    float* out = ws + cfg.off[s];
    int b_out = cfg.b_out[s];
    int colmode = cfg.colmode[s];
    int jm = cfg.jmaj[s];
    int nb = cfg.nb[s];
    int l = b % b_out, j = b / b_out;
    double beta = cfg.beta0[s] + cfg.bstep[s] * j;

    float x   = (float)cos(beta);
    float lsb = (float)log(sin(0.5 * beta));
    float lcb = (float)log(cos(0.5 * beta));
    int dim = 2*l + 1;
    long long S  = SF(b_out);
    long long Ol = SF(l);
    long long b2 = (long long)b_out * b_out;
    int total = colmode ? dim : dim * dim;
    for (int t = threadIdx.x; t < total; t += blockDim.x) {
        int mi, ni;
        if (colmode) { mi = t; ni = l; }
        else         { mi = t / dim; ni = t % dim; }
        int mp = mi - l, mm = ni - l;
        int k1 = l + mm, k2 = l - mm, k3 = l + mp, k4 = l - mp;
        int kk = min(min(k1, k2), min(k3, k4));
        int a, lam;
        if      (kk == k1) { a = mp - mm; lam = mp - mm; }
        else if (kk == k2) { a = mm - mp; lam = 0; }
        else if (kk == k3) { a = mm - mp; lam = 0; }
        else               { a = mp - mm; lam = mp - mm; }
        int bb = 2*l - 2*kk - a;
        float lpref = 0.5f * (lf[2*l - kk] + lf[kk] - lf[kk + a] - lf[kk + bb]);
        float P = 1.f;
        if (kk >= 1) {
            float fa = (float)a, fb = (float)bb;
            float p0 = 1.f;
            float p1 = 0.5f * ((fa - fb) + (fa + fb + 2.f) * x);
            for (int n = 2; n <= kk; n++) {
                float fn = (float)n;
                float t1 = 2.f*fn + fa + fb;
                float c1 = 2.f*fn*(fn + fa + fb)*(t1 - 2.f);
                float c2 = (t1 - 1.f) * (t1*(t1 - 2.f)*x + fa*fa - fb*fb);
                float c3 = 2.f*(fn + fa - 1.f)*(fn + fb - 1.f)*t1;
                float pn = (c2*p1 - c3*p0) / c1;
                p0 = p1; p1 = pn;
            }
            P = p1;
        }
        float val = expf(lpref + (float)a * lsb + (float)bb * lcb) * P;
        if (lam & 1) val = -val;
        long long e = colmode ? ((long long)l*l + mi) : (Ol + (long long)mi * dim + ni);
        long long idx;
        if (jm) idx = e * nb + j;
        else    idx = colmode ? ((long long)j * b2 + e) : ((long long)j * S + e);
        out[idx] = val;
    }
}

// ---------------- R25: Wigner for j-minor segments, j-as-lane ---------------
struct WigJmCfg {
    int nseg;
    int nblk[8];
    int off[8];
    int b_out[8];
    int colmode[8];
    int nb[8];
    int rc[8];
    double beta0[8];
    double bstep[8];
};

__global__ __launch_bounds__(256) void wigner_jm_kernel(float* __restrict__ ws, WigJmCfg cfg)
{
    __shared__ float lf[128];
    for (int t = threadIdx.x; t < 128; t += 256)
        lf[t] = (float)lgamma((double)t + 1.0);
    __syncthreads();

    int b = blockIdx.x, s = 0;
    while (b >= cfg.nblk[s]) { b -= cfg.nblk[s]; s++; }
    int b_out   = cfg.b_out[s];
    int colmode = cfg.colmode[s];
    int nb      = cfg.nb[s];
    int rc      = cfg.rc[s];
    float* out  = ws + cfg.off[s];

    int l = 0, chunk = b;
    for (; l < b_out; l++) {
        int dim = 2*l + 1;
        int etot = colmode ? dim : dim * dim;
        int nch = (etot + rc - 1) / rc;
        if (chunk < nch) break;
        chunk -= nch;
    }
    int dim  = 2*l + 1;
    int etot = colmode ? dim : dim * dim;
    int tid = threadIdx.x;
    int r = tid / nb, j = tid - r * nb;
    int el = chunk * rc + r;
    if (r >= rc || el >= etot) return;

    float beta = (float)(cfg.beta0[s] + cfg.bstep[s] * j);
    float x   = cosf(beta);
    float lsb = logf(sinf(0.5f * beta));
    float lcb = logf(cosf(0.5f * beta));

    int mi, ni;
    if (colmode) { mi = el; ni = l; }
    else         { mi = el / dim; ni = el - mi * dim; }
    int mp = mi - l, mm = ni - l;
    int k1 = l + mm, k2 = l - mm, k3 = l + mp, k4 = l - mp;
    int kk = min(min(k1, k2), min(k3, k4));
    int a, lam;
    if      (kk == k1) { a = mp - mm; lam = mp - mm; }
    else if (kk == k2) { a = mm - mp; lam = 0; }
    else if (kk == k3) { a = mm - mp; lam = 0; }
    else               { a = mp - mm; lam = mp - mm; }
    int bb = 2*l - 2*kk - a;
    float lpref = 0.5f * (lf[2*l - kk] + lf[kk] - lf[kk + a] - lf[kk + bb]);
    float P = 1.f;
    if (kk >= 1) {
        float fa = (float)a, fb = (float)bb;
        float p0 = 1.f;
        float p1 = 0.5f * ((fa - fb) + (fa + fb + 2.f) * x);
        for (int n = 2; n <= kk; n++) {
            float fn = (float)n;
            float t1 = 2.f*fn + fa + fb;
            float c1 = 2.f*fn*(fn + fa + fb)*(t1 - 2.f);
            float c2 = (t1 - 1.f) * (t1*(t1 - 2.f)*x + fa*fa - fb*fb);
            float c3 = 2.f*(fn + fa - 1.f)*(fn + fb - 1.f)*t1;
            float pn = (c2*p1 - c3*p0) / c1;
            p0 = p1; p1 = pn;
        }
        P = p1;
    }
    float val = expf(lpref + (float)a * lsb + (float)bb * lcb) * P;
    if (lam & 1) val = -val;
    long long e = colmode ? ((long long)l*l + mi)
                          : (SF(l) + (long long)mi * dim + ni);
    out[e * nb + j] = val;
}

// ---------------- setup: twiddles + DH weights in one launch ----------------
__global__ void setup_kernel(float2* __restrict__ W, float* __restrict__ w)
{
    int t = threadIdx.x + blockIdx.x * blockDim.x;
    if (t >= 110) return;
    const int Ns[4]   = {60, 30, 14, 6};
    const int offs[4] = {0, 60, 90, 104};
    int si = (t < 60) ? 0 : (t < 90) ? 1 : (t < 104) ? 2 : 3;
    int N = Ns[si];
    int k = t - offs[si];
    double ang = -2.0 * M_PI * (double)k / (double)N;
    W[t] = make_float2((float)cos(ang), (float)sin(ang));
    int b = N / 2;
    double beta = M_PI * (2*k + 1) / (4.0 * b);
    double s = 0.0;
    for (int kk = 0; kk < b; kk++) s += sin((2*kk + 1) * beta) / (2*kk + 1);
    w[t] = (float)((2.0 / b) * sin(beta) * s);
}

// ---------------- real-input forward DFT: [R, N] reals -> [R, NF] ----------
__global__ void dft_r_kernel(const float* __restrict__ in, float2* __restrict__ out,
                             const float2* __restrict__ Wt,
                             int R, int N, int NF, int RPB)
{
    __shared__ float s[2 * DFT_LDS];
    __shared__ float2 sW[64];
    int r0 = blockIdx.x * RPB;
    if (r0 >= R) return;
    int nr = min(RPB, R - r0);
    for (int t = threadIdx.x; t < N; t += blockDim.x) sW[t] = Wt[t];
    for (int t = threadIdx.x; t < nr * N; t += blockDim.x)
        s[t] = in[(long long)r0 * N + t];
    __syncthreads();
    for (int t = threadIdx.x; t < nr * NF; t += blockDim.x) {
        int rr = t / NF, f = t % NF;
        const float* row = s + rr * N;
        float re = 0.f, im = 0.f;
        int tw = 0;
        for (int n = 0; n < N; n++) {
            float2 w = sW[tw];
            float v = row[n];
            re += v * w.x;
            im += v * w.y;
            tw += f; if (tw >= N) tw -= N;
        }
        out[(long long)(r0 + rr) * NF + f] = make_float2(re, im);
    }
}

// ---------------- R27: fused 2-pass input FFT, radix-2 folded ---------------
__global__ void fft2_kernel(const float* __restrict__ in, float2* __restrict__ out,
                            const float2* __restrict__ Wt,
                            int R, int N, int C2, int SPB)
{
    extern __shared__ float sm[];
    float2* sW = (float2*)sm;                       // [N]
    float*  sIn = sm + 2 * N;                       // [SPB][N*N]
    float2* sMid = (float2*)(sIn + SPB * N * N);    // [SPB][N*C2]
    int tid = threadIdx.x;
    for (int t = tid; t < N; t += 256) sW[t] = Wt[t];
    int s0 = blockIdx.x * SPB;
    int ns = min(SPB, R - s0);
    if (ns <= 0) return;
    int slabIn = N * N;
    int H = N / 2;
    for (int t = tid; t < ns * slabIn; t += 256)
        sIn[t] = in[(long long)s0 * slabIn + t];
    __syncthreads();
    // ---- fold gamma in place ----
    int foldTot = ns * N * H;
    for (int t = tid; t < foldTot; t += 256) {
        int ss = t / (N * H), p = t - ss * (N * H);
        int a = p / H, r = p - a * H;
        float* base = sIn + ss * slabIn + a * N;
        float x0 = base[r], x1 = base[r + H];
        base[r]     = x0 + x1;
        base[r + H] = x0 - x1;
    }
    __syncthreads();
    // ---- pass 1: gamma DFT (n >= 0), halved ----
    int w1 = N * C2;
    for (int t = tid; t < ns * w1; t += 256) {
        int ss = t / w1, p = t - ss * w1;
        int a = p / C2, n = p - a * C2;
        const float* row = sIn + ss * slabIn + a * N + (n & 1) * H;
        float re = 0.f, im = 0.f;
        int tw = 0;
        for (int g = 0; g < H; g++) {
            float2 w = sW[tw];
            float v = row[g];
            re += v * w.x;
            im += v * w.y;
            tw += n; if (tw >= N) tw -= N;
        }
        sMid[ss * w1 + a * C2 + n] = make_float2(re, im);
    }
    __syncthreads();
    // ---- fold alpha in sMid ----
    int fold2 = ns * H * C2;
    for (int t = tid; t < fold2; t += 256) {
        int ss = t / (H * C2), p = t - ss * (H * C2);
        int r = p / C2, n = p - r * C2;
        float2* b0 = &sMid[ss * w1 + r * C2 + n];
        float2* b1 = &sMid[ss * w1 + (r + H) * C2 + n];
        float2 v0 = *b0, v1 = *b1;
        *b0 = make_float2(v0.x + v1.x, v0.y + v1.y);
        *b1 = make_float2(v0.x - v1.x, v0.y - v1.y);
    }
    __syncthreads();
    // ---- pass 2: alpha DFT (m >= 0), halved, dual accumulation for +-n ----
    int M = 2 * C2 - 1;
    int oslab = C2 * M;
    int w2 = C2 * C2;
    for (int t = tid; t < ns * w2; t += 256) {
        int ss = t / w2, p = t - ss * w2;
        int m = p / C2, npos = p - m * C2;
        const float2* col = sMid + ss * w1 + (m & 1) * H * C2 + npos;
        float r1 = 0.f, i1 = 0.f, r2 = 0.f, i2 = 0.f;
        int tw = 0;
        for (int a = 0; a < H; a++) {
            float2 w = sW[tw];
            float2 v = col[a * C2];
            r1 += v.x * w.x - v.y * w.y;
            i1 += v.x * w.y + v.y * w.x;
            r2 += v.x * w.x + v.y * w.y;
            i2 += v.y * w.x - v.x * w.y;
            tw += m; if (tw >= N) tw -= N;
        }
        float2* ob = out + (long long)(s0 + ss) * oslab + (long long)m * M;
        ob[(C2 - 1) + npos] = make_float2(r1, i1);
        if (npos > 0) ob[(C2 - 1) - npos] = make_float2(r2, -i2);
    }
}

// ---------------- xh (Wigner analysis of input), rows mi >= l only ----------
__global__ void xh_so3_kernel(const float2* __restrict__ xf, const float* __restrict__ din,
                              const float* __restrict__ wq, float2* __restrict__ xh,
                              int B, int Ci, int Nin, int b_out, int eMul, int jMul)
{
    int l = blockIdx.y;
    int dim = 2*l + 1;
    int M = 2*b_out - 1;
    long long S = SF(b_out), Ol = SF(l);
    int rows = l + 1;
    int total = B * Ci * rows * dim;
    int idx = blockIdx.x * blockDim.x + threadIdx.x;
    if (idx >= total) return;
    int ni  = idx % dim;
    int mip = (idx / dim) % rows;
    int bc  = idx / (dim * rows);
    int mi  = mip + l;
    int mf  = mip;
    int nf  = ni - l + (b_out - 1);
    float re = 0.f, im = 0.f;
    const float2* xb = xf + ((long long)bc * Nin) * b_out * M + (long long)mf * M + nf;
    const float*  db = din + (Ol + (long long)mi * dim + ni) * eMul;
    for (int j = 0; j < Nin; j++) {
        float dv = db[(long long)j * jMul] * wq[j];
        float2 xv = xb[(long long)j * b_out * M];
        re += dv * xv.x; im += dv * xv.y;
    }
    xh[(long long)bc * S + Ol + (long long)mi * dim + ni] = make_float2(re, im);
}

__global__ void xh_s2_kernel(const float2* __restrict__ xf, const float* __restrict__ dincol,
                             const float* __restrict__ wq, float2* __restrict__ xh,
                             int B, int Ci, int Nin, int b_out, int eMul, int jMul)
{
    int l = blockIdx.y;
    int b2 = b_out * b_out;
    int rows = l + 1;
    int total = B * Ci * rows;
    int idx = blockIdx.x * blockDim.x + threadIdx.x;
    if (idx >= total) return;
    int mip = idx % rows;
    int bc  = idx / rows;
    int mi  = mip + l;
    int mf  = mip;
    const float* db = dincol + ((long long)l*l + mi) * eMul;
    float re = 0.f, im = 0.f;
    for (int j = 0; j < Nin; j++) {
        float dv = db[(long long)j * jMul] * wq[j];
        float2 xv = xf[((long long)bc * Nin + j) * b_out + mf];
        re += dv * xv.x; im += dv * xv.y;
    }
    xh[(long long)bc * b2 + (long long)l*l + mi] = make_float2(re, im);
}

// ---------------- Y = dg * kf (kf inlined): per l, [i][ki][o*dim+ni] --------
__global__ void y_so3_direct(const float* __restrict__ kw, const float* __restrict__ dg,
                             float2* __restrict__ Y, int Ci, int Co, int b_out)
{
    const float cr[6] = {1.f, .5f, -.5f, -1.f, -.5f, .5f};
    const float ci_[6] = {0.f, -0.8660254037844386f, -0.8660254037844386f, 0.f,
                          0.8660254037844386f, 0.8660254037844386f};
    int l = blockIdx.y;
    int dim = 2*l + 1;
    long long Ol = SF(l);
    int Nd = Co * dim;
    int total = Ci * dim * Nd;
    int idx = blockIdx.x * blockDim.x + threadIdx.x;
    if (idx >= total) return;
    int col  = idx % Nd;
    int krow = idx / Nd;
    int ki = krow % dim, i = krow / dim;
    int o  = col / dim,  ni = col % dim;
    float dgv = dg[Ol + (long long)ni * dim + ki];
    int m = ni - l, n = ki - l;
    const float* kb = kw + (long long)(i*Co + o) * 36;
    int step = imod(2 * n, 6);
    float re = 0.f, im = 0.f;
    for (int a = 0; a < 6; a++) {
        int tt = imod(a * (m - n), 6);
        #pragma unroll
        for (int g = 0; g < 6; g++) {
            float kv = kb[a*6 + g];
            re += kv * cr[tt]; im += kv * ci_[tt];
            tt += step; if (tt >= 6) tt -= 6;
        }
    }
    Y[(long long)Ci * Co * Ol + idx] = make_float2(dgv * re, dgv * im);
}

// ---------------- z = xh · conj(Y), split-K over Ci (R23) -------------------
__global__ void z_so3_gemm(const float2* __restrict__ xh, const float2* __restrict__ Y,
                           float2* __restrict__ z, float2* __restrict__ zpart,
                           int B, int Ci, int Co, int b_out, int KS, long long partStride)
{
    int l = b_out - 1 - blockIdx.z;
    int dim = 2*l + 1;
    int rows = l + 1;
    long long S = SF(b_out), Ol = SF(l);
    int Nd = Co * dim;
    int c0 = blockIdx.x * 64;
    if (c0 >= Nd) return;
    int by = blockIdx.y;
    int b  = by % B;
    int kc = by / B;
    int ck = Ci / KS;
    int i0 = kc * ck;
    int tid = threadIdx.x;
    int cc = tid & 63;
    int mg = tid >> 6;
    int col = c0 + cc;
    __shared__ float2 sA[32 * 29];
    __shared__ float2 sY[29 * 64];
    float2 acc[8];
    #pragma unroll
    for (int r = 0; r < 8; r++) acc[r] = make_float2(0.f, 0.f);
    const float2* Yl = Y + (long long)Ci * Co * Ol;
    int rd = rows * dim;
    for (int i = i0; i < i0 + ck; i++) {
        const float2* Ab = xh + ((long long)(b*Ci + i)) * S + Ol + (long long)l * dim;
        for (int t = tid; t < 32 * dim; t += 256)
            sA[t] = (t < rd) ? Ab[t] : make_float2(0.f, 0.f);
        const float2* Yb = Yl + (long long)i * dim * Nd;
        for (int t = tid; t < dim * 64; t += 256) {
            int ki = t >> 6, c = t & 63;
            int gc = c0 + c;
            sY[t] = (gc < Nd) ? Yb[(long long)ki * Nd + gc] : make_float2(0.f, 0.f);
        }
        __syncthreads();
        for (int ki = 0; ki < dim; ki++) {
            float2 y = sY[ki*64 + cc];
            #pragma unroll
            for (int r = 0; r < 8; r++) {
                if (r*4 + mg < rows) {
                    float2 a = sA[(r*4 + mg) * dim + ki];
                    acc[r].x += a.x * y.x + a.y * y.y;
                    acc[r].y += a.y * y.x - a.x * y.y;
                }
            }
        }
        __syncthreads();
    }
    if (col < Nd) {
        float2* zo = (kc == 0) ? z : (zpart + (long long)(kc - 1) * partStride);
        long long base = ((long long)(b*Co + (col / dim))) * S + Ol + (col % dim);
        #pragma unroll
        for (int r = 0; r < 8; r++) {
            int mip = r*4 + mg;
            if (mip < rows) zo[base + (long long)(mip + l) * dim] = acc[r];
        }
    }
}

// ---------------- R23: fold split-K partials into z -------------------------
__global__ void z_reduce(float2* __restrict__ z, const float2* __restrict__ zpart,
                         long long total, long long partStride, int KS)
{
    long long idx = (long long)blockIdx.x * 256 + threadIdx.x;
    if (idx >= total) return;
    float2 a = z[idx];
    for (int k = 0; k < KS - 1; k++) {
        float2 p = zpart[(long long)k * partStride + idx];
        a.x += p.x; a.y += p.y;
    }
    z[idx] = a;
}

// ---------------- z for S2 layer (kf inlined, Ci small) ---------------------
__global__ void z_s2_direct(const float2* __restrict__ xh, const float* __restrict__ kw,
                            const float* __restrict__ dg, float2* __restrict__ z,
                            int B, int Ci, int Co, int b_out)
{
    const float cr[6] = {1.f, .5f, -.5f, -1.f, -.5f, .5f};
    const float ci_[6] = {0.f, -0.8660254037844386f, -0.8660254037844386f, 0.f,
                          0.8660254037844386f, 0.8660254037844386f};
    int l = blockIdx.y;
    int dim = 2*l + 1;
    int b2 = b_out * b_out;
    int rows = l + 1;
    long long S = SF(b_out), Ol = SF(l);
    int total = B * Co * rows * dim;
    int idx = blockIdx.x * blockDim.x + threadIdx.x;
    if (idx >= total) return;
    int ni  = idx % dim;
    int mip = (idx / dim) % rows;
    int o   = (idx / (dim * rows)) % Co;
    int b   = idx / (dim * rows * Co);
    int mi  = mip + l;
    float dgv = dg[Ol + (long long)ni * dim + l];
    int m = ni - l;
    int step = imod(m, 6);
    float sre = 0.f, sim = 0.f;
    for (int i = 0; i < Ci; i++) {
        const float* kb = kw + (long long)(i*Co + o) * 6;
        float kre = 0.f, kim = 0.f;
        int tt = 0;
        #pragma unroll
        for (int p = 0; p < 6; p++) {
            float kv = kb[p];
            kre += kv * cr[tt]; kim += kv * ci_[tt];
            tt += step; if (tt >= 6) tt -= 6;
        }
        float2 xv = xh[(long long)(b*Ci + i) * b2 + (long long)l*l + mi];
        sre += xv.x * kre + xv.y * kim;
        sim += xv.y * kre - xv.x * kim;
    }
    z[((long long)(b*Co + o)) * S + Ol + (long long)mi * dim + ni] = make_float2(dgv * sre, dgv * sim);
}

// ---------------- fused Hermitian output synthesis (R10: DIF+fold) ----------
// (still used for N=14 and N=6)
template<int N, int ROWS, int GS, int PPB, int BLK>
__global__ __launch_bounds__(BLK) void synth_t(
    const float2* __restrict__ z, const float* __restrict__ dout,
    const float2* __restrict__ Wt, float* __restrict__ act, int nPlanes)
{
    __shared__ float2 sP1[PPB][ROWS * N];
    __shared__ float2 sW[N];
    int tid = threadIdx.x;
    for (int t = tid; t < N; t += BLK) sW[t] = Wt[t];
    int lane = tid & 63, wave = tid >> 6;
    int sub = lane / GS, g = lane - sub * GS;
    int lp = wave * (64 / GS) + sub;
    int P = blockIdx.x * PPB + lp;
    bool on = (P < nPlanes);
    int bo = on ? (P / N) : 0, j = on ? (P - (P / N) * N) : 0;
    long long S = SF(ROWS);
    const float* dj = dout + (long long)j * S;
    const float2* zb = z + (long long)bo * S;
    float2* P1 = sP1[lp];
    for (int t = g; t < ROWS * N; t += GS) P1[t] = make_float2(0.f, 0.f);
    if (on) {
        for (int l = 0; l < ROWS; l++) {
            int dim = 2*l + 1;
            int run = (l + 1) * dim;
            long long base = SF(l) + (long long)l * dim;
            float fdim = (float)dim;
            float rdim = 1.f / fdim;
            for (int s0 = 0; s0 < run; s0 += GS) {
                int s = s0 + g;
                if (s < run) {
                    int m = (int)((float)s * rdim);
                    int rem = s - m * dim;
                    if (rem < 0)         { m--; rem += dim; }
                    else if (rem >= dim) { m++; rem -= dim; }
                    int q = rem - l; if (q < 0) q += N;
                    long long e = base + s;
                    float dv = dj[e] * fdim;
                    float2 zv = zb[e];
                    float2 cur = P1[m * N + q];
                    cur.x += dv * zv.x; cur.y += dv * zv.y;
                    P1[m * N + q] = cur;
                }
            }
        }
    }
    __syncthreads();
    if (on) {
        for (int t = g; t < ROWS * (N/2); t += GS) {
            int mm = t / (N/2), qp = t - mm * (N/2);
            int row = mm * N;
            float2 a = P1[row + qp];
            float2 b = P1[row + qp + N/2];
            float2 w = sW[qp];
            float2 d = make_float2(a.x - b.x, a.y - b.y);
            P1[row + qp]       = make_float2(a.x + b.x, a.y + b.y);
            P1[row + qp + N/2] = make_float2(d.x * w.x + d.y * w.y,
                                             d.y * w.x - d.x * w.y);
        }
    }
    __syncthreads();
    float2 acc[ROWS];
    #pragma unroll
    for (int m = 0; m < ROWS; m++) acc[m] = make_float2(0.f, 0.f);
    bool act_ = on && (g < N);
    if (act_) {
        int par = g & 1, gp = g >> 1;
        int off = par * (N/2);
        float2 wv = make_float2(1.f, 0.f);
        float2 wg = sW[2 * gp]; wg.y = -wg.y;
        for (int qp = 0; qp < N/2; qp++) {
            #pragma unroll
            for (int m = 0; m < ROWS; m++) {
                float2 v = P1[m * N + off + qp];
                acc[m].x += v.x * wv.x - v.y * wv.y;
                acc[m].y += v.x * wv.y + v.y * wv.x;
            }
            float nx = wv.x * wg.x - wv.y * wg.y;
            wv.y = wv.x * wg.y + wv.y * wg.x;
            wv.x = nx;
        }
    }
    if (!act_) return;
    float* ob = act + ((long long)bo * N + j) * (N * N);
    for (int a = 0; a < N/2; a++) {
        float se = 0.f, so = 0.f;
        int t0 = 0;
        #pragma unroll
        for (int m = 1; m < ROWS; m++) {
            t0 += a; if (t0 >= N) t0 -= N;
            float vx = acc[m].x + acc[m].x;
            float vy = acc[m].y + acc[m].y;
            float2 w0 = sW[t0];
            float term = vx * w0.x + vy * w0.y;
            if (m & 1) so += term; else se += term;
        }
        float base = acc[0].x;
        ob[a * N + g]         = fmaxf(base + se + so, 0.f);
        ob[(a + N/2) * N + g] = fmaxf(base + se - so, 0.f);
    }
}

// ---------------- R24: G-build for N=60, j-batched, coalesced ---------------
__global__ __launch_bounds__(512) void g_build60(
    const float2* __restrict__ z, const float* __restrict__ doutT,
    float2* __restrict__ G)
{
    const int ROWS = 30;
    const long long S = 35990;                 // SF(30)
    int bo  = blockIdx.x;
    int mq0 = blockIdx.y * 8;
    int tid = threadIdx.x;
    int r = tid / 60, j = tid - r * 60;
    __shared__ float2 sT[480];
    if (r < 8) {
        float2 acc = make_float2(0.f, 0.f);
        int mq = mq0 + r;
        int m = mq / 60, q = mq - m * 60;
        int n = (q <= 30) ? q : q - 60;
        int an = (n < 0) ? -n : n;
        int l0 = (m > an) ? m : an;
        if (l0 < ROWS) {
            const float2* zb = z + (long long)bo * S;
            int e  = l0*(4*l0*l0 - 1)/3 + (l0 + m)*(2*l0 + 1) + (n + l0);
            int de = 4*l0*l0 + 8*l0 + 2*m + 5;
            int dd = 8*l0 + 12;
            float fl = (float)(2*l0 + 1);
            for (int l = l0; l < ROWS; l++) {
                float dv = doutT[(long long)e * 60 + j] * fl;
                float2 zv = zb[e];
                acc.x += dv * zv.x; acc.y += dv * zv.y;
                e += de; de += dd; dd += 8; fl += 2.f;
            }
        }
        sT[j * 8 + r] = acc;
    }
    __syncthreads();
    if (tid < 480) {
        int j2 = tid >> 3, r2 = tid & 7;
        G[((long long)(bo * 60 + j2)) * 1800 + mq0 + r2] = sT[tid];
    }
}

// ---------------- R28: N=60 synthesis phases 2-4, m-outer phase 4 -----------
__global__ __launch_bounds__(256) void synth60b_kernel(
    const float2* __restrict__ G, const float2* __restrict__ Wt,
    float* __restrict__ act, int nPlanes)
{
    const int N = 60, ROWS = 30;
    __shared__ float2 sP1[ROWS * N];
    __shared__ float2 sW[N];
    int tid = threadIdx.x;
    for (int t = tid; t < N; t += 256) sW[t] = Wt[t];
    int P = blockIdx.x;
    if (P >= nPlanes) return;
    const float2* Gp = G + (long long)P * 1800;
    for (int t = tid; t < ROWS * N; t += 256) sP1[t] = Gp[t];
    __syncthreads();

    // ---- DIF stage 1 (60 -> 2x30) ----
    for (int t = tid; t < ROWS * 30; t += 256) {
        int mm = t / 30, qp = t - mm * 30;
        int row = mm * N;
        float2 a = sP1[row + qp];
        float2 b = sP1[row + qp + 30];
        float2 w = sW[qp];
        float2 d = make_float2(a.x - b.x, a.y - b.y);
        sP1[row + qp]      = make_float2(a.x + b.x, a.y + b.y);
        sP1[row + qp + 30] = make_float2(d.x * w.x + d.y * w.y,
                                         d.y * w.x - d.x * w.y);
    }
    __syncthreads();
    // ---- DIF stage 2 (30 -> 2x15 in each half) ----
    for (int t = tid; t < ROWS * 30; t += 256) {
        int mm = t / 30, sub = t - mm * 30;
        int h = sub / 15, r = sub - h * 15;
        int base = mm * N + h * 30;
        float2 c0 = sP1[base + r];
        float2 c1 = sP1[base + r + 15];
        float2 w = sW[2 * r];
        float2 d = make_float2(c0.x - c1.x, c0.y - c1.y);
        sP1[base + r]      = make_float2(c0.x + c1.x, c0.y + c1.y);
        sP1[base + r + 15] = make_float2(d.x * w.x + d.y * w.y,
                                         d.y * w.x - d.x * w.y);
    }
    __syncthreads();

    int lane = tid & 63, wave = tid >> 6;
    int g = lane;
    int m0 = wave * 8;
    int cnt = (ROWS - m0 < 8) ? (ROWS - m0) : 8;

    // ---- 15-pt DFT per (row, g); write P2 IN PLACE into sP1 ----
    if (g < N) {
        float2 pacc[8];
        #pragma unroll
        for (int mm = 0; mm < 8; mm++) pacc[mm] = make_float2(0.f, 0.f);
        int off = (g & 1) * 30 + ((g >> 1) & 1) * 15;
        float2 wg = sW[4 * (g >> 2)]; wg.y = -wg.y;
        float2 wv = make_float2(1.f, 0.f);
        for (int r = 0; r < 15; r++) {
            #pragma unroll
            for (int mm = 0; mm < 8; mm++) {
                if (mm < cnt) {
                    float2 v = sP1[(m0 + mm) * N + off + r];
                    pacc[mm].x += v.x * wv.x - v.y * wv.y;
                    pacc[mm].y += v.x * wv.y + v.y * wv.x;
                }
            }
            float nx = wv.x * wg.x - wv.y * wg.y;
            wv.y = wv.x * wg.y + wv.y * wg.x;
            wv.x = nx;
        }
        #pragma unroll
        for (int mm = 0; mm < 8; mm++) {
            if (mm < cnt) sP1[(m0 + mm) * N + g] = pacc[mm];
        }
    }
    __syncthreads();

    // ---- phase 4: beta synthesis, m-outer / 4-a-inner, mirror rows ----
    if (g < N) {
        float bx = sP1[g].x;
        float ec[4] = {0.f, 0.f, 0.f, 0.f}, es[4] = {0.f, 0.f, 0.f, 0.f};
        float oc[4] = {0.f, 0.f, 0.f, 0.f}, os[4] = {0.f, 0.f, 0.f, 0.f};
        int t0[4] = {0, 0, 0, 0};
        int a0 = wave * 4;
        #pragma unroll
        for (int m = 1; m < ROWS; m++) {
            float2 v = sP1[m * N + g];
            #pragma unroll
            for (int ii = 0; ii < 4; ii++) {
                t0[ii] += a0 + ii; if (t0[ii] >= N) t0[ii] -= N;
                float2 w0 = sW[t0[ii]];
                if (m & 1) { oc[ii] += v.x * w0.x; os[ii] += v.y * w0.y; }
                else       { ec[ii] += v.x * w0.x; es[ii] += v.y * w0.y; }
            }
        }
        float* ob = act + (long long)P * (N * N);
        #pragma unroll
        for (int ii = 0; ii < 4; ii++) {
            int a = a0 + ii;                  // a in [0,15]
            float ep_ = ec[ii] + es[ii], em = ec[ii] - es[ii];
            float op_ = oc[ii] + os[ii], om = oc[ii] - os[ii];
            ob[a * N + g]        = fmaxf(bx + 2.f * (ep_ + op_), 0.f);
            ob[(a + 30) * N + g] = fmaxf(bx + 2.f * (ep_ - op_), 0.f);
            if (a != 0 && a != 15) {
                ob[(30 - a) * N + g] = fmaxf(bx + 2.f * (em - om), 0.f);
                ob[(60 - a) * N + g] = fmaxf(bx + 2.f * (em + om), 0.f);
            }
        }
    }
}

// ---------------- R28: N=30 synthesis (layers 1-2), m-outer phase 4 ---------
__global__ __launch_bounds__(256) void synth30_kernel(
    const float2* __restrict__ z, const float* __restrict__ dout,
    const float2* __restrict__ Wt, float* __restrict__ act, int nPlanes)
{
    const int N = 30, ROWS = 15;
    __shared__ float2 sStage[2360];           // sum_{l<15} (l+1)(2l+1)
    __shared__ float2 sP1[ROWS * N];          // 450
    __shared__ float2 sW[N];
    int tid = threadIdx.x;
    for (int t = tid; t < N; t += 256) sW[t] = Wt[t];
    int P = blockIdx.x;
    if (P >= nPlanes) return;
    int bo = P / N, j = P - bo * N;
    long long S = SF(ROWS);                   // 4495
    const float* dj = dout + (long long)j * S;
    const float2* zb = z + (long long)bo * S;

    for (int l = 0; l < ROWS; l++) {
        int dimn = 2 * l + 1;
        int run  = (l + 1) * dimn;
        int base = l * (4 * l * l - 1) / 3 + l * dimn;
        int so   = l * (4 * l * l + 3 * l - 1) / 6;
        for (int t = tid; t < run; t += 256) {
            float d   = dj[base + t];
            float2 zv = zb[base + t];
            sStage[so + t] = make_float2(d * zv.x, d * zv.y);
        }
    }
    __syncthreads();

    float2 acc[2];
    #pragma unroll
    for (int p = 0; p < 2; p++) {
        acc[p] = make_float2(0.f, 0.f);
        int idx = tid + p * 256;
        if (idx < ROWS * N) {
            int m = idx / N, q = idx - m * N;
            int n = (q <= 15) ? q : q - 30;
            int an = (n < 0) ? -n : n;
            int l0 = (m > an) ? m : an;
            if (l0 < ROWS) {
                int e  = l0 * (4*l0*l0 + 3*l0 - 1) / 6 + m * (2*l0 + 1) + n + l0;
                int de = (l0 + 1) * (2*l0 + 1) + 2*m + 1;
                int dd = 4 * l0 + 5;
                float fl = (float)(2*l0 + 1);
                for (int l = l0; l < ROWS; l++) {
                    float2 v = sStage[e];
                    acc[p].x += fl * v.x; acc[p].y += fl * v.y;
                    e += de; de += dd; dd += 4; fl += 2.f;
                }
            }
        }
    }
    #pragma unroll
    for (int p = 0; p < 2; p++) {
        int idx = tid + p * 256;
        if (idx < ROWS * N) sP1[idx] = acc[p];
    }
    __syncthreads();

    for (int t = tid; t < ROWS * 15; t += 256) {
        int mm = t / 15, qp = t - mm * 15;
        int row = mm * N;
        float2 a = sP1[row + qp];
        float2 b = sP1[row + qp + 15];
        float2 w = sW[qp];
        float2 d = make_float2(a.x - b.x, a.y - b.y);
        sP1[row + qp]      = make_float2(a.x + b.x, a.y + b.y);
        sP1[row + qp + 15] = make_float2(d.x * w.x + d.y * w.y,
                                         d.y * w.x - d.x * w.y);
    }
    __syncthreads();

    int lane = tid & 63, wave = tid >> 6;
    int g = lane;
    int m0 = wave * 4;
    int cnt = (ROWS - m0 < 4) ? (ROWS - m0) : 4;   // 4,4,4,3

    if (g < N) {
        float2 pacc[4];
        #pragma unroll
        for (int mm = 0; mm < 4; mm++) pacc[mm] = make_float2(0.f, 0.f);
        int off = (g & 1) * 15;
        float2 wg = sW[2 * (g >> 1)]; wg.y = -wg.y;
        float2 wv = make_float2(1.f, 0.f);
        for (int r = 0; r < 15; r++) {
            #pragma unroll
            for (int mm = 0; mm < 4; mm++) {
                if (mm < cnt) {
                    float2 v = sP1[(m0 + mm) * N + off + r];
                    pacc[mm].x += v.x * wv.x - v.y * wv.y;
                    pacc[mm].y += v.x * wv.y + v.y * wv.x;
                }
            }
            float nx = wv.x * wg.x - wv.y * wg.y;
            wv.y = wv.x * wg.y + wv.y * wg.x;
            wv.x = nx;
        }
        #pragma unroll
        for (int mm = 0; mm < 4; mm++) {
            if (mm < cnt) sP1[(m0 + mm) * N + g] = pacc[mm];
        }
    }
    __syncthreads();

    // ---- phase 4: beta synthesis, m-outer / 2-a-inner, mirror rows ----
    if (g < N) {
        float bx = sP1[g].x;
        float ec[2] = {0.f, 0.f}, es[2] = {0.f, 0.f};
        float oc[2] = {0.f, 0.f}, os[2] = {0.f, 0.f};
        int t0[2] = {0, 0};
        int a0 = wave * 2;
        #pragma unroll
        for (int m = 1; m < ROWS; m++) {
            float2 v = sP1[m * N + g];
            #pragma unroll
            for (int ii = 0; ii < 2; ii++) {
                t0[ii] += a0 + ii; if (t0[ii] >= N) t0[ii] -= N;
                float2 w0 = sW[t0[ii]];
                if (m & 1) { oc[ii] += v.x * w0.x; os[ii] += v.y * w0.y; }
                else       { ec[ii] += v.x * w0.x; es[ii] += v.y * w0.y; }
            }
        }
        float* ob = act + ((long long)bo * N + j) * (N * N);
        #pragma unroll
        for (int ii = 0; ii < 2; ii++) {
            int a = a0 + ii;                  // a in [0,7]
            float ep_ = ec[ii] + es[ii], em = ec[ii] - es[ii];
            float op_ = oc[ii] + os[ii], om = oc[ii] - os[ii];
            ob[a * N + g]        = fmaxf(bx + 2.f * (ep_ + op_), 0.f);
            ob[(a + 15) * N + g] = fmaxf(bx + 2.f * (ep_ - op_), 0.f);
            if (a != 0) {
                ob[(15 - a) * N + g] = fmaxf(bx + 2.f * (em - om), 0.f);
                ob[(30 - a) * N + g] = fmaxf(bx + 2.f * (em + om), 0.f);
            }
        }
    }
}

// ---------------- R21: grid-parallel SO3 integrate --------------------------
__global__ void integrate_kernel(const float* __restrict__ act,
                                 const float* __restrict__ wq,
                                 float* __restrict__ feat)
{
    int e = blockIdx.x;
    int lane = threadIdx.x;                   // 64
    const float* base = act + (size_t)e * 216;
    float acc = 0.f;
    for (int i = lane; i < 216; i += 64)
        acc += wq[104 + i / 36] * base[i];
    for (int off = 32; off; off >>= 1) acc += __shfl_down(acc, off);
    if (lane == 0) feat[e] = acc * (1.f / 36.f);
}

// ---------------- BN-MLP head (single block, integrate pre-done) ------------
__global__ void head_kernel(const float* __restrict__ featg,
    const float* __restrict__ g1, const float* __restrict__ be1,
    const float* __restrict__ w1, const float* __restrict__ b1,
    const float* __restrict__ g2, const float* __restrict__ be2,
    const float* __restrict__ w2, const float* __restrict__ b2,
    const float* __restrict__ g3, const float* __restrict__ be3,
    const float* __restrict__ w3, const float* __restrict__ b3,
    float* __restrict__ out)
{
    __shared__ float feat[512];
    __shared__ float xn[512];
    __shared__ float h1[512];
    __shared__ float h2[256];
    int tid = threadIdx.x;
    for (int t = tid; t < 512; t += blockDim.x) feat[t] = featg[t];
    __syncthreads();
    for (int c = tid; c < 64; c += blockDim.x) {
        float mu = 0.f;
        for (int b = 0; b < 8; b++) mu += feat[b*64 + c];
        mu *= 0.125f;
        float var = 0.f;
        for (int b = 0; b < 8; b++) { float d = feat[b*64 + c] - mu; var += d*d; }
        var *= 0.125f;
        float is = rsqrtf(var + 1e-5f);
        for (int b = 0; b < 8; b++) xn[b*64 + c] = g1[c] * (feat[b*64 + c] - mu) * is + be1[c];
    }
    __syncthreads();
    for (int t = tid; t < 512; t += blockDim.x) {
        int b = t >> 6, o = t & 63;
        float acc = b1[o];
        for (int i = 0; i < 64; i++) acc += xn[b*64 + i] * w1[i*64 + o];
        h1[t] = fmaxf(acc, 0.f);
    }
    __syncthreads();
    for (int c = tid; c < 64; c += blockDim.x) {
        float mu = 0.f;
        for (int b = 0; b < 8; b++) mu += h1[b*64 + c];
        mu *= 0.125f;
        float var = 0.f;
        for (int b = 0; b < 8; b++) { float d = h1[b*64 + c] - mu; var += d*d; }
        var *= 0.125f;
        float is = rsqrtf(var + 1e-5f);
        for (int b = 0; b < 8; b++) xn[b*64 + c] = g2[c] * (h1[b*64 + c] - mu) * is + be2[c];
    }
    __syncthreads();
    for (int t = tid; t < 256; t += blockDim.x) {
        int b = t >> 5, o = t & 31;
        float acc = b2[o];
        for (int i = 0; i < 64; i++) acc += xn[b*64 + i] * w2[i*32 + o];
        h2[t] = fmaxf(acc, 0.f);
    }
    __syncthreads();
    for (int c = tid; c < 32; c += blockDim.x) {
        float mu = 0.f;
        for (int b = 0; b < 8; b++) mu += h2[b*32 + c];
        mu *= 0.125f;
        float var = 0.f;
        for (int b = 0; b < 8; b++) { float d = h2[b*32 + c] - mu; var += d*d; }
        var *= 0.125f;
        float is = rsqrtf(var + 1e-5f);
        for (int b = 0; b < 8; b++) xn[b*32 + c] = g3[c] * (h2[b*32 + c] - mu) * is + be3[c];
    }
    __syncthreads();
    for (int t = tid; t < 80; t += blockDim.x) {
        int b = t / 10, o = t % 10;
        float acc = b3[o];
        for (int i = 0; i < 32; i++) acc += xn[b*32 + i] * w3[i*10 + o];
        out[t] = acc;
    }
}

// ---------------------------------------------------------------------------

static inline int hmin(int a, int b) { return a < b ? a : b; }
static inline int hmax(int a, int b) { return a > b ? a : b; }
static inline int twoff(int N) { return N == 60 ? 0 : N == 30 ? 60 : N == 14 ? 90 : 104; }
static inline int wqoffb(int b) { return b == 30 ? 0 : b == 15 ? 60 : b == 7 ? 90 : 104; }

extern "C" void kernel_launch(void* const* d_in, const int* in_sizes, int n_in,
                              void* d_out, int out_size, void* d_ws, size_t ws_size,
                              hipStream_t stream)
{
    (void)in_sizes; (void)n_in; (void)out_size;
    const double PI = 3.14159265358979323846;
    struct LD { int kind, b_in, b_out, Ci, Co; double bg; };
    const LD LAY[7] = {
        {0, 30, 30,  1,  8, PI/16},
        {1, 30, 15,  8, 16, PI/16},
        {1, 15, 15, 16, 16, PI/8},
        {1, 15,  7, 16, 24, PI/8},
        {1,  7,  7, 24, 24, PI/4},
        {1,  7,  3, 24, 32, PI/4},
        {1,  3,  3, 32, 64, PI/2},
    };

    float* ws = (float*)d_ws;
    size_t off = 0;
    auto alloc = [&](size_t n) -> size_t { size_t o = off; off += (n + 63) & ~(size_t)63; return o; };
    size_t oA    = alloc(13400000);   // Y buffer; +oB span = layer-0 G buffer
    size_t oB    = alloc(8200000);    // input spectrum / z split-K partials
    size_t oAct1 = alloc(13824000);
    size_t oAct2 = alloc(3456000);
    size_t oXH   = alloc(1200000);
    size_t oZ    = alloc(4800000);
    size_t oWQ   = alloc(128);
    size_t oTW   = alloc(256);
    size_t oFeat = alloc(512);
    size_t oDin[7], oDout[7], oDg[7];
    for (int i = 0; i < 7; i++) {
        const LD& L = LAY[i];
        long long S = SF(L.b_out);
        bool reuse = (i == 2 || i == 4 || i == 6);
        if (reuse) {
            oDin[i]  = oDout[i-1];
            oDout[i] = oDout[i-1];
        } else {
            size_t din_sz = (L.kind == 0) ? (size_t)(2*L.b_in) * L.b_out * L.b_out
                                          : (size_t)(2*L.b_in) * S;
            oDin[i]  = alloc(din_sz);
            oDout[i] = alloc((size_t)(2*L.b_out) * S);
        }
        oDg[i]   = alloc((size_t)S);
    }
    if ((off + 64) * sizeof(float) > ws_size) return;

    float2* TW = (float2*)(ws + oTW);
    float*  WQ = ws + oWQ;

    setup_kernel<<<1, 128, 0, stream>>>(TW, WQ);

    WigCfg cfg;
    WigJmCfg jcfg;
    int ns = 0, totBlk = 0, njs = 0, jTot = 0;
    auto addSeg = [&](int nblk, size_t o, int b_out, int colmode, int jmaj, int nb,
                      double b0, double bs) {
        cfg.nblk[ns] = nblk; cfg.off[ns] = (int)o; cfg.b_out[ns] = b_out;
        cfg.colmode[ns] = colmode; cfg.jmaj[ns] = jmaj; cfg.nb[ns] = nb;
        cfg.beta0[ns] = b0; cfg.bstep[ns] = bs;
        ns++; totBlk += nblk;
    };
    auto addJmSeg = [&](size_t o, int b_out, int colmode, int nb,
                        double b0, double bs) {
        int rc = 256 / nb;
        int blocks = 0;
        for (int l = 0; l < b_out; l++) {
            int dim = 2*l + 1;
            int etot = colmode ? dim : dim * dim;
            blocks += (etot + rc - 1) / rc;
        }
        jcfg.nblk[njs] = blocks; jcfg.off[njs] = (int)o; jcfg.b_out[njs] = b_out;
        jcfg.colmode[njs] = colmode; jcfg.nb[njs] = nb; jcfg.rc[njs] = rc;
        jcfg.beta0[njs] = b0; jcfg.bstep[njs] = bs;
        njs++; jTot += blocks;
    };
    for (int i = 0; i < 7; i++) {
        const LD& L = LAY[i];
        bool reuse = (i == 2 || i == 4 || i == 6);
        if (!reuse) {
            // din: j-minor [e][nb]
            addJmSeg(oDin[i], L.b_out, (L.kind == 0) ? 1 : 0, 2*L.b_in,
                     PI/(4.0*L.b_in), PI/(2.0*L.b_in));
            if (i == 0) {
                // layer-0 dout j-minor [e][60] for g_build60
                addJmSeg(oDout[0], L.b_out, 0, 2*L.b_out,
                         PI/(4.0*L.b_out), PI/(2.0*L.b_out));
            } else {
                addSeg(2*L.b_out * L.b_out, oDout[i], L.b_out, 0, 0,
                       2*L.b_out, PI/(4.0*L.b_out), PI/(2.0*L.b_out));
            }
        }
        addSeg(L.b_out, oDg[i], L.b_out, 0, 0, 1, L.bg, 0.0);
    }
    cfg.nseg = ns;
    jcfg.nseg = njs;
    wigner_all_kernel<<<totBlk, 128, 0, stream>>>(ws, cfg);
    wigner_jm_kernel<<<jTot, 256, 0, stream>>>(ws, jcfg);

    const int Bt = 8;
    const float* cur = (const float*)d_in[0];
    float* actbuf[2] = { ws + oAct1, ws + oAct2 };

    for (int i = 0; i < 7; i++) {
        const LD& L = LAY[i];
        int Nin = 2*L.b_in, Nout = 2*L.b_out, M = 2*L.b_out - 1;
        float2* Bb = (float2*)(ws + oB);
        float2* XH = (float2*)(ws + oXH);
        float2* Z  = (float2*)(ws + oZ);
        const float2* TWin  = TW + twoff(Nin);
        const float2* TWout = TW + twoff(Nout);
        const float*  wql   = WQ + wqoffb(L.b_in);
        const float*  kw    = (const float*)d_in[1 + i];
        float* actOut = actbuf[i & 1];
        bool reuse = (i == 2 || i == 4 || i == 6);
        int eMul = reuse ? 1 : Nin;
        int jMul = reuse ? (int)SF(L.b_out) : 1;

        if (L.kind == 0) {
            int R = Bt * L.Ci * Nin;
            int RPB = hmin(R, hmax(1, 2 * DFT_LDS / Nin));
            dft_r_kernel<<<(R + RPB - 1) / RPB, 256, 0, stream>>>(
                cur, Bb, TWin, R, Nin, L.b_out, RPB);
            int gx = (Bt * L.Ci * L.b_out + 255) / 256;
            xh_s2_kernel<<<dim3(gx, L.b_out), 256, 0, stream>>>(
                Bb, ws + oDin[i], wql, XH, Bt, L.Ci, Nin, L.b_out, eMul, jMul);
            int gz = (Bt * L.Co * L.b_out * M + 255) / 256;
            z_s2_direct<<<dim3(gz, L.b_out), 256, 0, stream>>>(
                XH, kw, ws + oDg[i], Z, Bt, L.Ci, L.Co, L.b_out);
        } else {
            // fused 2-pass input FFT (gamma n>=0 + alpha dual +-n), radix-2
            int Rs = Bt * L.Ci * Nin;     // slabs of [alpha=Nin][gamma=Nin]
            int SPB = (Nin >= 60) ? 1 : (Nin >= 30) ? 2 : (Nin >= 14) ? 8 : 16;
            size_t lds = (size_t)Nin * sizeof(float2)
                       + (size_t)SPB * ((size_t)Nin * Nin * sizeof(float)
                                        + (size_t)Nin * L.b_out * sizeof(float2));
            fft2_kernel<<<(Rs + SPB - 1) / SPB, 256, lds, stream>>>(
                cur, Bb, TWin, Rs, Nin, L.b_out, SPB);
            int gx = (Bt * L.Ci * L.b_out * M + 255) / 256;
            xh_so3_kernel<<<dim3(gx, L.b_out), 256, 0, stream>>>(
                Bb, ws + oDin[i], wql, XH, Bt, L.Ci, Nin, L.b_out, eMul, jMul);
            float2* Yb = (float2*)(ws + oA);
            int ty = L.Ci * M * L.Co * M;
            y_so3_direct<<<dim3((ty + 255) / 256, L.b_out), 256, 0, stream>>>(
                kw, ws + oDg[i], Yb, L.Ci, L.Co, L.b_out);
            // R23: split-K z-GEMM; partials in the dead oB buffer.
            const int KS = 4;
            long long partF2 = (long long)Bt * L.Co * SF(L.b_out);
            float2* Zp = (float2*)(ws + oB);
            int ntiles = (L.Co * M + 63) / 64;
            z_so3_gemm<<<dim3(ntiles, Bt * KS, L.b_out), 256, 0, stream>>>(
                XH, Yb, Z, Zp, Bt, L.Ci, L.Co, L.b_out, KS, partF2);
            int rb = (int)((partF2 + 255) / 256);
            z_reduce<<<rb, 256, 0, stream>>>(Z, Zp, partF2, partF2, KS);
        }

        int planes = Bt * L.Co * Nout;
        if (Nout == 60) {
            // R24: G-build (j-batched, coalesced) + phases 2-4 kernel.
            float2* Gb = (float2*)(ws + oA);
            g_build60<<<dim3(Bt * L.Co, 225), 512, 0, stream>>>(
                Z, ws + oDout[i], Gb);
            synth60b_kernel<<<planes, 256, 0, stream>>>(Gb, TWout, actOut, planes);
        } else if (Nout == 30) {
            synth30_kernel<<<planes, 256, 0, stream>>>(Z, ws + oDout[i], TWout, actOut, planes);
        } else if (Nout == 14) {
            synth_t<14, 7,16,4, 64><<<(planes + 3) / 4,  64, 0, stream>>>(Z, ws + oDout[i], TWout, actOut, planes);
        } else {
            synth_t< 6, 3, 8,8, 64><<<(planes + 7) / 8,  64, 0, stream>>>(Z, ws + oDout[i], TWout, actOut, planes);
        }
        cur = actOut;
    }

    integrate_kernel<<<512, 64, 0, stream>>>(cur, WQ, ws + oFeat);

    head_kernel<<<1, 256, 0, stream>>>(
        ws + oFeat,
        (const float*)d_in[8],  (const float*)d_in[9],  (const float*)d_in[10], (const float*)d_in[11],
        (const float*)d_in[12], (const float*)d_in[13], (const float*)d_in[14], (const float*)d_in[15],
        (const float*)d_in[16], (const float*)d_in[17], (const float*)d_in[18], (const float*)d_in[19],
        (float*)d_out);
}

// Round 15
// 1013.936 us; speedup vs baseline: 1.0426x; 1.0426x over previous
//
#include <hip/hip_runtime.h>
#include <math.h>

// ---------------------------------------------------------------------------
// S2ConvNet_deep: 7 spectral conv layers (1 S2 + 6 SO3) + SO3-integrate + MLP.
// All constant tables computed on-device every call (graph-capture safe).
// R1..R14: see git history (z-GEMM, fused synth, Hermitian halving, fft2).
// R15..R20: synth60 gather evolution (in-place P2, LDS 14.9KB, 180us).
// R21/R22: synth60 phase-1 pipeline; fp32 wigner; integrate pre-kernel (1369).
// R23: z_so3_gemm split-K + big-l-first -> 1040us.
// R24: g_build60 (j-batched coalesced G-build) + synth60b -> 1020us.
// R25/R26: wigner_jm_kernel (j-as-lane) -> wigner off the top-5.
// R27: radix-2 fold in both fft2 passes -> 1015us (measured best).
// R28 REVERTED: phase-4 m-outer interchange -> VGPR 44->124 (full unroll of
//      29-iter loop with 16 live accumulators), occupancy 21%, 110us.
//      Same failure mode as R19. Transformation permanently abandoned.
// R29: exact revert to R27 (a-outer scalar phase 4 in synth60b/synth30).
// ---------------------------------------------------------------------------

#define DFT_LDS 3712   // float2 slots for DFT staging (29.7 KB)

__host__ __device__ inline long long SF(int l) { return (long long)l * (4LL*l*l - 1) / 3; }
__device__ inline int imod(int a, int n) { int r = a % n; return r < 0 ? r + n : r; }

// ---------------- Wigner small-d, j-major segments (fp32 core) --------------
struct WigCfg {
    int nseg;
    int nblk[16];
    int off[16];
    int b_out[16];
    int colmode[16];
    int jmaj[16];
    int nb[16];
    double beta0[16];
    double bstep[16];
};

__global__ void wigner_all_kernel(float* __restrict__ ws, WigCfg cfg)
{
    __shared__ float lf[128];
    for (int t = threadIdx.x; t < 128; t += blockDim.x)
        lf[t] = (float)lgamma((double)t + 1.0);
    __syncthreads();

    int b = blockIdx.x, s = 0;
    while (b >= cfg.nblk[s]) { b -= cfg.nblk[s]; s++; }
    float* out = ws + cfg.off[s];
    int b_out = cfg.b_out[s];
    int colmode = cfg.colmode[s];
    int jm = cfg.jmaj[s];
    int nb = cfg.nb[s];
    int l = b % b_out, j = b / b_out;
    double beta = cfg.beta0[s] + cfg.bstep[s] * j;

    float x   = (float)cos(beta);
    float lsb = (float)log(sin(0.5 * beta));
    float lcb = (float)log(cos(0.5 * beta));
    int dim = 2*l + 1;
    long long S  = SF(b_out);
    long long Ol = SF(l);
    long long b2 = (long long)b_out * b_out;
    int total = colmode ? dim : dim * dim;
    for (int t = threadIdx.x; t < total; t += blockDim.x) {
        int mi, ni;
        if (colmode) { mi = t; ni = l; }
        else         { mi = t / dim; ni = t % dim; }
        int mp = mi - l, mm = ni - l;
        int k1 = l + mm, k2 = l - mm, k3 = l + mp, k4 = l - mp;
        int kk = min(min(k1, k2), min(k3, k4));
        int a, lam;
        if      (kk == k1) { a = mp - mm; lam = mp - mm; }
        else if (kk == k2) { a = mm - mp; lam = 0; }
        else if (kk == k3) { a = mm - mp; lam = 0; }
        else               { a = mp - mm; lam = mp - mm; }
        int bb = 2*l - 2*kk - a;
        float lpref = 0.5f * (lf[2*l - kk] + lf[kk] - lf[kk + a] - lf[kk + bb]);
        float P = 1.f;
        if (kk >= 1) {
            float fa = (float)a, fb = (float)bb;
            float p0 = 1.f;
            float p1 = 0.5f * ((fa - fb) + (fa + fb + 2.f) * x);
            for (int n = 2; n <= kk; n++) {
                float fn = (float)n;
                float t1 = 2.f*fn + fa + fb;
                float c1 = 2.f*fn*(fn + fa + fb)*(t1 - 2.f);
                float c2 = (t1 - 1.f) * (t1*(t1 - 2.f)*x + fa*fa - fb*fb);
                float c3 = 2.f*(fn + fa - 1.f)*(fn + fb - 1.f)*t1;
                float pn = (c2*p1 - c3*p0) / c1;
                p0 = p1; p1 = pn;
            }
            P = p1;
        }
        float val = expf(lpref + (float)a * lsb + (float)bb * lcb) * P;
        if (lam & 1) val = -val;
        long long e = colmode ? ((long long)l*l + mi) : (Ol + (long long)mi * dim + ni);
        long long idx;
        if (jm) idx = e * nb + j;
        else    idx = colmode ? ((long long)j * b2 + e) : ((long long)j * S + e);
        out[idx] = val;
    }
}

// ---------------- R25: Wigner for j-minor segments, j-as-lane ---------------
struct WigJmCfg {
    int nseg;
    int nblk[8];
    int off[8];
    int b_out[8];
    int colmode[8];
    int nb[8];
    int rc[8];
    double beta0[8];
    double bstep[8];
};

__global__ __launch_bounds__(256) void wigner_jm_kernel(float* __restrict__ ws, WigJmCfg cfg)
{
    __shared__ float lf[128];
    for (int t = threadIdx.x; t < 128; t += 256)
        lf[t] = (float)lgamma((double)t + 1.0);
    __syncthreads();

    int b = blockIdx.x, s = 0;
    while (b >= cfg.nblk[s]) { b -= cfg.nblk[s]; s++; }
    int b_out   = cfg.b_out[s];
    int colmode = cfg.colmode[s];
    int nb      = cfg.nb[s];
    int rc      = cfg.rc[s];
    float* out  = ws + cfg.off[s];

    int l = 0, chunk = b;
    for (; l < b_out; l++) {
        int dim = 2*l + 1;
        int etot = colmode ? dim : dim * dim;
        int nch = (etot + rc - 1) / rc;
        if (chunk < nch) break;
        chunk -= nch;
    }
    int dim  = 2*l + 1;
    int etot = colmode ? dim : dim * dim;
    int tid = threadIdx.x;
    int r = tid / nb, j = tid - r * nb;
    int el = chunk * rc + r;
    if (r >= rc || el >= etot) return;

    float beta = (float)(cfg.beta0[s] + cfg.bstep[s] * j);
    float x   = cosf(beta);
    float lsb = logf(sinf(0.5f * beta));
    float lcb = logf(cosf(0.5f * beta));

    int mi, ni;
    if (colmode) { mi = el; ni = l; }
    else         { mi = el / dim; ni = el - mi * dim; }
    int mp = mi - l, mm = ni - l;
    int k1 = l + mm, k2 = l - mm, k3 = l + mp, k4 = l - mp;
    int kk = min(min(k1, k2), min(k3, k4));
    int a, lam;
    if      (kk == k1) { a = mp - mm; lam = mp - mm; }
    else if (kk == k2) { a = mm - mp; lam = 0; }
    else if (kk == k3) { a = mm - mp; lam = 0; }
    else               { a = mp - mm; lam = mp - mm; }
    int bb = 2*l - 2*kk - a;
    float lpref = 0.5f * (lf[2*l - kk] + lf[kk] - lf[kk + a] - lf[kk + bb]);
    float P = 1.f;
    if (kk >= 1) {
        float fa = (float)a, fb = (float)bb;
        float p0 = 1.f;
        float p1 = 0.5f * ((fa - fb) + (fa + fb + 2.f) * x);
        for (int n = 2; n <= kk; n++) {
            float fn = (float)n;
            float t1 = 2.f*fn + fa + fb;
            float c1 = 2.f*fn*(fn + fa + fb)*(t1 - 2.f);
            float c2 = (t1 - 1.f) * (t1*(t1 - 2.f)*x + fa*fa - fb*fb);
            float c3 = 2.f*(fn + fa - 1.f)*(fn + fb - 1.f)*t1;
            float pn = (c2*p1 - c3*p0) / c1;
            p0 = p1; p1 = pn;
        }
        P = p1;
    }
    float val = expf(lpref + (float)a * lsb + (float)bb * lcb) * P;
    if (lam & 1) val = -val;
    long long e = colmode ? ((long long)l*l + mi)
                          : (SF(l) + (long long)mi * dim + ni);
    out[e * nb + j] = val;
}

// ---------------- setup: twiddles + DH weights in one launch ----------------
__global__ void setup_kernel(float2* __restrict__ W, float* __restrict__ w)
{
    int t = threadIdx.x + blockIdx.x * blockDim.x;
    if (t >= 110) return;
    const int Ns[4]   = {60, 30, 14, 6};
    const int offs[4] = {0, 60, 90, 104};
    int si = (t < 60) ? 0 : (t < 90) ? 1 : (t < 104) ? 2 : 3;
    int N = Ns[si];
    int k = t - offs[si];
    double ang = -2.0 * M_PI * (double)k / (double)N;
    W[t] = make_float2((float)cos(ang), (float)sin(ang));
    int b = N / 2;
    double beta = M_PI * (2*k + 1) / (4.0 * b);
    double s = 0.0;
    for (int kk = 0; kk < b; kk++) s += sin((2*kk + 1) * beta) / (2*kk + 1);
    w[t] = (float)((2.0 / b) * sin(beta) * s);
}

// ---------------- real-input forward DFT: [R, N] reals -> [R, NF] ----------
__global__ void dft_r_kernel(const float* __restrict__ in, float2* __restrict__ out,
                             const float2* __restrict__ Wt,
                             int R, int N, int NF, int RPB)
{
    __shared__ float s[2 * DFT_LDS];
    __shared__ float2 sW[64];
    int r0 = blockIdx.x * RPB;
    if (r0 >= R) return;
    int nr = min(RPB, R - r0);
    for (int t = threadIdx.x; t < N; t += blockDim.x) sW[t] = Wt[t];
    for (int t = threadIdx.x; t < nr * N; t += blockDim.x)
        s[t] = in[(long long)r0 * N + t];
    __syncthreads();
    for (int t = threadIdx.x; t < nr * NF; t += blockDim.x) {
        int rr = t / NF, f = t % NF;
        const float* row = s + rr * N;
        float re = 0.f, im = 0.f;
        int tw = 0;
        for (int n = 0; n < N; n++) {
            float2 w = sW[tw];
            float v = row[n];
            re += v * w.x;
            im += v * w.y;
            tw += f; if (tw >= N) tw -= N;
        }
        out[(long long)(r0 + rr) * NF + f] = make_float2(re, im);
    }
}

// ---------------- R27: fused 2-pass input FFT, radix-2 folded ---------------
__global__ void fft2_kernel(const float* __restrict__ in, float2* __restrict__ out,
                            const float2* __restrict__ Wt,
                            int R, int N, int C2, int SPB)
{
    extern __shared__ float sm[];
    float2* sW = (float2*)sm;                       // [N]
    float*  sIn = sm + 2 * N;                       // [SPB][N*N]
    float2* sMid = (float2*)(sIn + SPB * N * N);    // [SPB][N*C2]
    int tid = threadIdx.x;
    for (int t = tid; t < N; t += 256) sW[t] = Wt[t];
    int s0 = blockIdx.x * SPB;
    int ns = min(SPB, R - s0);
    if (ns <= 0) return;
    int slabIn = N * N;
    int H = N / 2;
    for (int t = tid; t < ns * slabIn; t += 256)
        sIn[t] = in[(long long)s0 * slabIn + t];
    __syncthreads();
    // ---- fold gamma in place ----
    int foldTot = ns * N * H;
    for (int t = tid; t < foldTot; t += 256) {
        int ss = t / (N * H), p = t - ss * (N * H);
        int a = p / H, r = p - a * H;
        float* base = sIn + ss * slabIn + a * N;
        float x0 = base[r], x1 = base[r + H];
        base[r]     = x0 + x1;
        base[r + H] = x0 - x1;
    }
    __syncthreads();
    // ---- pass 1: gamma DFT (n >= 0), halved ----
    int w1 = N * C2;
    for (int t = tid; t < ns * w1; t += 256) {
        int ss = t / w1, p = t - ss * w1;
        int a = p / C2, n = p - a * C2;
        const float* row = sIn + ss * slabIn + a * N + (n & 1) * H;
        float re = 0.f, im = 0.f;
        int tw = 0;
        for (int g = 0; g < H; g++) {
            float2 w = sW[tw];
            float v = row[g];
            re += v * w.x;
            im += v * w.y;
            tw += n; if (tw >= N) tw -= N;
        }
        sMid[ss * w1 + a * C2 + n] = make_float2(re, im);
    }
    __syncthreads();
    // ---- fold alpha in sMid ----
    int fold2 = ns * H * C2;
    for (int t = tid; t < fold2; t += 256) {
        int ss = t / (H * C2), p = t - ss * (H * C2);
        int r = p / C2, n = p - r * C2;
        float2* b0 = &sMid[ss * w1 + r * C2 + n];
        float2* b1 = &sMid[ss * w1 + (r + H) * C2 + n];
        float2 v0 = *b0, v1 = *b1;
        *b0 = make_float2(v0.x + v1.x, v0.y + v1.y);
        *b1 = make_float2(v0.x - v1.x, v0.y - v1.y);
    }
    __syncthreads();
    // ---- pass 2: alpha DFT (m >= 0), halved, dual accumulation for +-n ----
    int M = 2 * C2 - 1;
    int oslab = C2 * M;
    int w2 = C2 * C2;
    for (int t = tid; t < ns * w2; t += 256) {
        int ss = t / w2, p = t - ss * w2;
        int m = p / C2, npos = p - m * C2;
        const float2* col = sMid + ss * w1 + (m & 1) * H * C2 + npos;
        float r1 = 0.f, i1 = 0.f, r2 = 0.f, i2 = 0.f;
        int tw = 0;
        for (int a = 0; a < H; a++) {
            float2 w = sW[tw];
            float2 v = col[a * C2];
            r1 += v.x * w.x - v.y * w.y;
            i1 += v.x * w.y + v.y * w.x;
            r2 += v.x * w.x + v.y * w.y;
            i2 += v.y * w.x - v.x * w.y;
            tw += m; if (tw >= N) tw -= N;
        }
        float2* ob = out + (long long)(s0 + ss) * oslab + (long long)m * M;
        ob[(C2 - 1) + npos] = make_float2(r1, i1);
        if (npos > 0) ob[(C2 - 1) - npos] = make_float2(r2, -i2);
    }
}

// ---------------- xh (Wigner analysis of input), rows mi >= l only ----------
__global__ void xh_so3_kernel(const float2* __restrict__ xf, const float* __restrict__ din,
                              const float* __restrict__ wq, float2* __restrict__ xh,
                              int B, int Ci, int Nin, int b_out, int eMul, int jMul)
{
    int l = blockIdx.y;
    int dim = 2*l + 1;
    int M = 2*b_out - 1;
    long long S = SF(b_out), Ol = SF(l);
    int rows = l + 1;
    int total = B * Ci * rows * dim;
    int idx = blockIdx.x * blockDim.x + threadIdx.x;
    if (idx >= total) return;
    int ni  = idx % dim;
    int mip = (idx / dim) % rows;
    int bc  = idx / (dim * rows);
    int mi  = mip + l;
    int mf  = mip;
    int nf  = ni - l + (b_out - 1);
    float re = 0.f, im = 0.f;
    const float2* xb = xf + ((long long)bc * Nin) * b_out * M + (long long)mf * M + nf;
    const float*  db = din + (Ol + (long long)mi * dim + ni) * eMul;
    for (int j = 0; j < Nin; j++) {
        float dv = db[(long long)j * jMul] * wq[j];
        float2 xv = xb[(long long)j * b_out * M];
        re += dv * xv.x; im += dv * xv.y;
    }
    xh[(long long)bc * S + Ol + (long long)mi * dim + ni] = make_float2(re, im);
}

__global__ void xh_s2_kernel(const float2* __restrict__ xf, const float* __restrict__ dincol,
                             const float* __restrict__ wq, float2* __restrict__ xh,
                             int B, int Ci, int Nin, int b_out, int eMul, int jMul)
{
    int l = blockIdx.y;
    int b2 = b_out * b_out;
    int rows = l + 1;
    int total = B * Ci * rows;
    int idx = blockIdx.x * blockDim.x + threadIdx.x;
    if (idx >= total) return;
    int mip = idx % rows;
    int bc  = idx / rows;
    int mi  = mip + l;
    int mf  = mip;
    const float* db = dincol + ((long long)l*l + mi) * eMul;
    float re = 0.f, im = 0.f;
    for (int j = 0; j < Nin; j++) {
        float dv = db[(long long)j * jMul] * wq[j];
        float2 xv = xf[((long long)bc * Nin + j) * b_out + mf];
        re += dv * xv.x; im += dv * xv.y;
    }
    xh[(long long)bc * b2 + (long long)l*l + mi] = make_float2(re, im);
}

// ---------------- Y = dg * kf (kf inlined): per l, [i][ki][o*dim+ni] --------
__global__ void y_so3_direct(const float* __restrict__ kw, const float* __restrict__ dg,
                             float2* __restrict__ Y, int Ci, int Co, int b_out)
{
    const float cr[6] = {1.f, .5f, -.5f, -1.f, -.5f, .5f};
    const float ci_[6] = {0.f, -0.8660254037844386f, -0.8660254037844386f, 0.f,
                          0.8660254037844386f, 0.8660254037844386f};
    int l = blockIdx.y;
    int dim = 2*l + 1;
    long long Ol = SF(l);
    int Nd = Co * dim;
    int total = Ci * dim * Nd;
    int idx = blockIdx.x * blockDim.x + threadIdx.x;
    if (idx >= total) return;
    int col  = idx % Nd;
    int krow = idx / Nd;
    int ki = krow % dim, i = krow / dim;
    int o  = col / dim,  ni = col % dim;
    float dgv = dg[Ol + (long long)ni * dim + ki];
    int m = ni - l, n = ki - l;
    const float* kb = kw + (long long)(i*Co + o) * 36;
    int step = imod(2 * n, 6);
    float re = 0.f, im = 0.f;
    for (int a = 0; a < 6; a++) {
        int tt = imod(a * (m - n), 6);
        #pragma unroll
        for (int g = 0; g < 6; g++) {
            float kv = kb[a*6 + g];
            re += kv * cr[tt]; im += kv * ci_[tt];
            tt += step; if (tt >= 6) tt -= 6;
        }
    }
    Y[(long long)Ci * Co * Ol + idx] = make_float2(dgv * re, dgv * im);
}

// ---------------- z = xh · conj(Y), split-K over Ci (R23) -------------------
__global__ void z_so3_gemm(const float2* __restrict__ xh, const float2* __restrict__ Y,
                           float2* __restrict__ z, float2* __restrict__ zpart,
                           int B, int Ci, int Co, int b_out, int KS, long long partStride)
{
    int l = b_out - 1 - blockIdx.z;
    int dim = 2*l + 1;
    int rows = l + 1;
    long long S = SF(b_out), Ol = SF(l);
    int Nd = Co * dim;
    int c0 = blockIdx.x * 64;
    if (c0 >= Nd) return;
    int by = blockIdx.y;
    int b  = by % B;
    int kc = by / B;
    int ck = Ci / KS;
    int i0 = kc * ck;
    int tid = threadIdx.x;
    int cc = tid & 63;
    int mg = tid >> 6;
    int col = c0 + cc;
    __shared__ float2 sA[32 * 29];
    __shared__ float2 sY[29 * 64];
    float2 acc[8];
    #pragma unroll
    for (int r = 0; r < 8; r++) acc[r] = make_float2(0.f, 0.f);
    const float2* Yl = Y + (long long)Ci * Co * Ol;
    int rd = rows * dim;
    for (int i = i0; i < i0 + ck; i++) {
        const float2* Ab = xh + ((long long)(b*Ci + i)) * S + Ol + (long long)l * dim;
        for (int t = tid; t < 32 * dim; t += 256)
            sA[t] = (t < rd) ? Ab[t] : make_float2(0.f, 0.f);
        const float2* Yb = Yl + (long long)i * dim * Nd;
        for (int t = tid; t < dim * 64; t += 256) {
            int ki = t >> 6, c = t & 63;
            int gc = c0 + c;
            sY[t] = (gc < Nd) ? Yb[(long long)ki * Nd + gc] : make_float2(0.f, 0.f);
        }
        __syncthreads();
        for (int ki = 0; ki < dim; ki++) {
            float2 y = sY[ki*64 + cc];
            #pragma unroll
            for (int r = 0; r < 8; r++) {
                if (r*4 + mg < rows) {
                    float2 a = sA[(r*4 + mg) * dim + ki];
                    acc[r].x += a.x * y.x + a.y * y.y;
                    acc[r].y += a.y * y.x - a.x * y.y;
                }
            }
        }
        __syncthreads();
    }
    if (col < Nd) {
        float2* zo = (kc == 0) ? z : (zpart + (long long)(kc - 1) * partStride);
        long long base = ((long long)(b*Co + (col / dim))) * S + Ol + (col % dim);
        #pragma unroll
        for (int r = 0; r < 8; r++) {
            int mip = r*4 + mg;
            if (mip < rows) zo[base + (long long)(mip + l) * dim] = acc[r];
        }
    }
}

// ---------------- R23: fold split-K partials into z -------------------------
__global__ void z_reduce(float2* __restrict__ z, const float2* __restrict__ zpart,
                         long long total, long long partStride, int KS)
{
    long long idx = (long long)blockIdx.x * 256 + threadIdx.x;
    if (idx >= total) return;
    float2 a = z[idx];
    for (int k = 0; k < KS - 1; k++) {
        float2 p = zpart[(long long)k * partStride + idx];
        a.x += p.x; a.y += p.y;
    }
    z[idx] = a;
}

// ---------------- z for S2 layer (kf inlined, Ci small) ---------------------
__global__ void z_s2_direct(const float2* __restrict__ xh, const float* __restrict__ kw,
                            const float* __restrict__ dg, float2* __restrict__ z,
                            int B, int Ci, int Co, int b_out)
{
    const float cr[6] = {1.f, .5f, -.5f, -1.f, -.5f, .5f};
    const float ci_[6] = {0.f, -0.8660254037844386f, -0.8660254037844386f, 0.f,
                          0.8660254037844386f, 0.8660254037844386f};
    int l = blockIdx.y;
    int dim = 2*l + 1;
    int b2 = b_out * b_out;
    int rows = l + 1;
    long long S = SF(b_out), Ol = SF(l);
    int total = B * Co * rows * dim;
    int idx = blockIdx.x * blockDim.x + threadIdx.x;
    if (idx >= total) return;
    int ni  = idx % dim;
    int mip = (idx / dim) % rows;
    int o   = (idx / (dim * rows)) % Co;
    int b   = idx / (dim * rows * Co);
    int mi  = mip + l;
    float dgv = dg[Ol + (long long)ni * dim + l];
    int m = ni - l;
    int step = imod(m, 6);
    float sre = 0.f, sim = 0.f;
    for (int i = 0; i < Ci; i++) {
        const float* kb = kw + (long long)(i*Co + o) * 6;
        float kre = 0.f, kim = 0.f;
        int tt = 0;
        #pragma unroll
        for (int p = 0; p < 6; p++) {
            float kv = kb[p];
            kre += kv * cr[tt]; kim += kv * ci_[tt];
            tt += step; if (tt >= 6) tt -= 6;
        }
        float2 xv = xh[(long long)(b*Ci + i) * b2 + (long long)l*l + mi];
        sre += xv.x * kre + xv.y * kim;
        sim += xv.y * kre - xv.x * kim;
    }
    z[((long long)(b*Co + o)) * S + Ol + (long long)mi * dim + ni] = make_float2(dgv * sre, dgv * sim);
}

// ---------------- fused Hermitian output synthesis (R10: DIF+fold) ----------
// (still used for N=14 and N=6)
template<int N, int ROWS, int GS, int PPB, int BLK>
__global__ __launch_bounds__(BLK) void synth_t(
    const float2* __restrict__ z, const float* __restrict__ dout,
    const float2* __restrict__ Wt, float* __restrict__ act, int nPlanes)
{
    __shared__ float2 sP1[PPB][ROWS * N];
    __shared__ float2 sW[N];
    int tid = threadIdx.x;
    for (int t = tid; t < N; t += BLK) sW[t] = Wt[t];
    int lane = tid & 63, wave = tid >> 6;
    int sub = lane / GS, g = lane - sub * GS;
    int lp = wave * (64 / GS) + sub;
    int P = blockIdx.x * PPB + lp;
    bool on = (P < nPlanes);
    int bo = on ? (P / N) : 0, j = on ? (P - (P / N) * N) : 0;
    long long S = SF(ROWS);
    const float* dj = dout + (long long)j * S;
    const float2* zb = z + (long long)bo * S;
    float2* P1 = sP1[lp];
    for (int t = g; t < ROWS * N; t += GS) P1[t] = make_float2(0.f, 0.f);
    if (on) {
        for (int l = 0; l < ROWS; l++) {
            int dim = 2*l + 1;
            int run = (l + 1) * dim;
            long long base = SF(l) + (long long)l * dim;
            float fdim = (float)dim;
            float rdim = 1.f / fdim;
            for (int s0 = 0; s0 < run; s0 += GS) {
                int s = s0 + g;
                if (s < run) {
                    int m = (int)((float)s * rdim);
                    int rem = s - m * dim;
                    if (rem < 0)         { m--; rem += dim; }
                    else if (rem >= dim) { m++; rem -= dim; }
                    int q = rem - l; if (q < 0) q += N;
                    long long e = base + s;
                    float dv = dj[e] * fdim;
                    float2 zv = zb[e];
                    float2 cur = P1[m * N + q];
                    cur.x += dv * zv.x; cur.y += dv * zv.y;
                    P1[m * N + q] = cur;
                }
            }
        }
    }
    __syncthreads();
    if (on) {
        for (int t = g; t < ROWS * (N/2); t += GS) {
            int mm = t / (N/2), qp = t - mm * (N/2);
            int row = mm * N;
            float2 a = P1[row + qp];
            float2 b = P1[row + qp + N/2];
            float2 w = sW[qp];
            float2 d = make_float2(a.x - b.x, a.y - b.y);
            P1[row + qp]       = make_float2(a.x + b.x, a.y + b.y);
            P1[row + qp + N/2] = make_float2(d.x * w.x + d.y * w.y,
                                             d.y * w.x - d.x * w.y);
        }
    }
    __syncthreads();
    float2 acc[ROWS];
    #pragma unroll
    for (int m = 0; m < ROWS; m++) acc[m] = make_float2(0.f, 0.f);
    bool act_ = on && (g < N);
    if (act_) {
        int par = g & 1, gp = g >> 1;
        int off = par * (N/2);
        float2 wv = make_float2(1.f, 0.f);
        float2 wg = sW[2 * gp]; wg.y = -wg.y;
        for (int qp = 0; qp < N/2; qp++) {
            #pragma unroll
            for (int m = 0; m < ROWS; m++) {
                float2 v = P1[m * N + off + qp];
                acc[m].x += v.x * wv.x - v.y * wv.y;
                acc[m].y += v.x * wv.y + v.y * wv.x;
            }
            float nx = wv.x * wg.x - wv.y * wg.y;
            wv.y = wv.x * wg.y + wv.y * wg.x;
            wv.x = nx;
        }
    }
    if (!act_) return;
    float* ob = act + ((long long)bo * N + j) * (N * N);
    for (int a = 0; a < N/2; a++) {
        float se = 0.f, so = 0.f;
        int t0 = 0;
        #pragma unroll
        for (int m = 1; m < ROWS; m++) {
            t0 += a; if (t0 >= N) t0 -= N;
            float vx = acc[m].x + acc[m].x;
            float vy = acc[m].y + acc[m].y;
            float2 w0 = sW[t0];
            float term = vx * w0.x + vy * w0.y;
            if (m & 1) so += term; else se += term;
        }
        float base = acc[0].x;
        ob[a * N + g]         = fmaxf(base + se + so, 0.f);
        ob[(a + N/2) * N + g] = fmaxf(base + se - so, 0.f);
    }
}

// ---------------- R24: G-build for N=60, j-batched, coalesced ---------------
__global__ __launch_bounds__(512) void g_build60(
    const float2* __restrict__ z, const float* __restrict__ doutT,
    float2* __restrict__ G)
{
    const int ROWS = 30;
    const long long S = 35990;                 // SF(30)
    int bo  = blockIdx.x;
    int mq0 = blockIdx.y * 8;
    int tid = threadIdx.x;
    int r = tid / 60, j = tid - r * 60;
    __shared__ float2 sT[480];
    if (r < 8) {
        float2 acc = make_float2(0.f, 0.f);
        int mq = mq0 + r;
        int m = mq / 60, q = mq - m * 60;
        int n = (q <= 30) ? q : q - 60;
        int an = (n < 0) ? -n : n;
        int l0 = (m > an) ? m : an;
        if (l0 < ROWS) {
            const float2* zb = z + (long long)bo * S;
            int e  = l0*(4*l0*l0 - 1)/3 + (l0 + m)*(2*l0 + 1) + (n + l0);
            int de = 4*l0*l0 + 8*l0 + 2*m + 5;
            int dd = 8*l0 + 12;
            float fl = (float)(2*l0 + 1);
            for (int l = l0; l < ROWS; l++) {
                float dv = doutT[(long long)e * 60 + j] * fl;
                float2 zv = zb[e];
                acc.x += dv * zv.x; acc.y += dv * zv.y;
                e += de; de += dd; dd += 8; fl += 2.f;
            }
        }
        sT[j * 8 + r] = acc;
    }
    __syncthreads();
    if (tid < 480) {
        int j2 = tid >> 3, r2 = tid & 7;
        G[((long long)(bo * 60 + j2)) * 1800 + mq0 + r2] = sT[tid];
    }
}

// ---------------- R24/R27: N=60 synthesis phases 2-4 only -------------------
__global__ __launch_bounds__(256) void synth60b_kernel(
    const float2* __restrict__ G, const float2* __restrict__ Wt,
    float* __restrict__ act, int nPlanes)
{
    const int N = 60, ROWS = 30;
    __shared__ float2 sP1[ROWS * N];
    __shared__ float2 sW[N];
    int tid = threadIdx.x;
    for (int t = tid; t < N; t += 256) sW[t] = Wt[t];
    int P = blockIdx.x;
    if (P >= nPlanes) return;
    const float2* Gp = G + (long long)P * 1800;
    for (int t = tid; t < ROWS * N; t += 256) sP1[t] = Gp[t];
    __syncthreads();

    // ---- DIF stage 1 (60 -> 2x30) ----
    for (int t = tid; t < ROWS * 30; t += 256) {
        int mm = t / 30, qp = t - mm * 30;
        int row = mm * N;
        float2 a = sP1[row + qp];
        float2 b = sP1[row + qp + 30];
        float2 w = sW[qp];
        float2 d = make_float2(a.x - b.x, a.y - b.y);
        sP1[row + qp]      = make_float2(a.x + b.x, a.y + b.y);
        sP1[row + qp + 30] = make_float2(d.x * w.x + d.y * w.y,
                                         d.y * w.x - d.x * w.y);
    }
    __syncthreads();
    // ---- DIF stage 2 (30 -> 2x15 in each half) ----
    for (int t = tid; t < ROWS * 30; t += 256) {
        int mm = t / 30, sub = t - mm * 30;
        int h = sub / 15, r = sub - h * 15;
        int base = mm * N + h * 30;
        float2 c0 = sP1[base + r];
        float2 c1 = sP1[base + r + 15];
        float2 w = sW[2 * r];
        float2 d = make_float2(c0.x - c1.x, c0.y - c1.y);
        sP1[base + r]      = make_float2(c0.x + c1.x, c0.y + c1.y);
        sP1[base + r + 15] = make_float2(d.x * w.x + d.y * w.y,
                                         d.y * w.x - d.x * w.y);
    }
    __syncthreads();

    int lane = tid & 63, wave = tid >> 6;
    int g = lane;
    int m0 = wave * 8;
    int cnt = (ROWS - m0 < 8) ? (ROWS - m0) : 8;

    // ---- 15-pt DFT per (row, g); write P2 IN PLACE into sP1 ----
    if (g < N) {
        float2 pacc[8];
        #pragma unroll
        for (int mm = 0; mm < 8; mm++) pacc[mm] = make_float2(0.f, 0.f);
        int off = (g & 1) * 30 + ((g >> 1) & 1) * 15;
        float2 wg = sW[4 * (g >> 2)]; wg.y = -wg.y;
        float2 wv = make_float2(1.f, 0.f);
        for (int r = 0; r < 15; r++) {
            #pragma unroll
            for (int mm = 0; mm < 8; mm++) {
                if (mm < cnt) {
                    float2 v = sP1[(m0 + mm) * N + off + r];
                    pacc[mm].x += v.x * wv.x - v.y * wv.y;
                    pacc[mm].y += v.x * wv.y + v.y * wv.x;
                }
            }
            float nx = wv.x * wg.x - wv.y * wg.y;
            wv.y = wv.x * wg.y + wv.y * wg.x;
            wv.x = nx;
        }
        #pragma unroll
        for (int mm = 0; mm < 8; mm++) {
            if (mm < cnt) sP1[(m0 + mm) * N + g] = pacc[mm];
        }
    }
    __syncthreads();

    // ---- phase 4: beta synthesis, a-outer scalars, mirror rows ----
    if (g < N) {
        float bx = sP1[g].x;
        float* ob = act + (long long)P * (N * N);
        for (int ii = 0; ii < 4; ii++) {
            int a = wave * 4 + ii;            // a in [0,15]
            float se_c = 0.f, se_s = 0.f, so_c = 0.f, so_s = 0.f;
            int t0 = 0;
            #pragma unroll
            for (int m = 1; m < ROWS; m++) {
                t0 += a; if (t0 >= N) t0 -= N;
                float2 w0 = sW[t0];
                float2 v = sP1[m * N + g];
                if (m & 1) { so_c += v.x * w0.x; so_s += v.y * w0.y; }
                else       { se_c += v.x * w0.x; se_s += v.y * w0.y; }
            }
            float ep_ = se_c + se_s, em = se_c - se_s;
            float op_ = so_c + so_s, om = so_c - so_s;
            ob[a * N + g]        = fmaxf(bx + 2.f * (ep_ + op_), 0.f);
            ob[(a + 30) * N + g] = fmaxf(bx + 2.f * (ep_ - op_), 0.f);
            if (a != 0 && a != 15) {
                ob[(30 - a) * N + g] = fmaxf(bx + 2.f * (em - om), 0.f);
                ob[(60 - a) * N + g] = fmaxf(bx + 2.f * (em + om), 0.f);
            }
        }
    }
}

// ---------------- R20/R27: N=30 synthesis (layers 1-2) ----------------------
__global__ __launch_bounds__(256) void synth30_kernel(
    const float2* __restrict__ z, const float* __restrict__ dout,
    const float2* __restrict__ Wt, float* __restrict__ act, int nPlanes)
{
    const int N = 30, ROWS = 15;
    __shared__ float2 sStage[2360];           // sum_{l<15} (l+1)(2l+1)
    __shared__ float2 sP1[ROWS * N];          // 450
    __shared__ float2 sW[N];
    int tid = threadIdx.x;
    for (int t = tid; t < N; t += 256) sW[t] = Wt[t];
    int P = blockIdx.x;
    if (P >= nPlanes) return;
    int bo = P / N, j = P - bo * N;
    long long S = SF(ROWS);                   // 4495
    const float* dj = dout + (long long)j * S;
    const float2* zb = z + (long long)bo * S;

    for (int l = 0; l < ROWS; l++) {
        int dimn = 2 * l + 1;
        int run  = (l + 1) * dimn;
        int base = l * (4 * l * l - 1) / 3 + l * dimn;
        int so   = l * (4 * l * l + 3 * l - 1) / 6;
        for (int t = tid; t < run; t += 256) {
            float d   = dj[base + t];
            float2 zv = zb[base + t];
            sStage[so + t] = make_float2(d * zv.x, d * zv.y);
        }
    }
    __syncthreads();

    float2 acc[2];
    #pragma unroll
    for (int p = 0; p < 2; p++) {
        acc[p] = make_float2(0.f, 0.f);
        int idx = tid + p * 256;
        if (idx < ROWS * N) {
            int m = idx / N, q = idx - m * N;
            int n = (q <= 15) ? q : q - 30;
            int an = (n < 0) ? -n : n;
            int l0 = (m > an) ? m : an;
            if (l0 < ROWS) {
                int e  = l0 * (4*l0*l0 + 3*l0 - 1) / 6 + m * (2*l0 + 1) + n + l0;
                int de = (l0 + 1) * (2*l0 + 1) + 2*m + 1;
                int dd = 4 * l0 + 5;
                float fl = (float)(2*l0 + 1);
                for (int l = l0; l < ROWS; l++) {
                    float2 v = sStage[e];
                    acc[p].x += fl * v.x; acc[p].y += fl * v.y;
                    e += de; de += dd; dd += 4; fl += 2.f;
                }
            }
        }
    }
    #pragma unroll
    for (int p = 0; p < 2; p++) {
        int idx = tid + p * 256;
        if (idx < ROWS * N) sP1[idx] = acc[p];
    }
    __syncthreads();

    for (int t = tid; t < ROWS * 15; t += 256) {
        int mm = t / 15, qp = t - mm * 15;
        int row = mm * N;
        float2 a = sP1[row + qp];
        float2 b = sP1[row + qp + 15];
        float2 w = sW[qp];
        float2 d = make_float2(a.x - b.x, a.y - b.y);
        sP1[row + qp]      = make_float2(a.x + b.x, a.y + b.y);
        sP1[row + qp + 15] = make_float2(d.x * w.x + d.y * w.y,
                                         d.y * w.x - d.x * w.y);
    }
    __syncthreads();

    int lane = tid & 63, wave = tid >> 6;
    int g = lane;
    int m0 = wave * 4;
    int cnt = (ROWS - m0 < 4) ? (ROWS - m0) : 4;   // 4,4,4,3

    if (g < N) {
        float2 pacc[4];
        #pragma unroll
        for (int mm = 0; mm < 4; mm++) pacc[mm] = make_float2(0.f, 0.f);
        int off = (g & 1) * 15;
        float2 wg = sW[2 * (g >> 1)]; wg.y = -wg.y;
        float2 wv = make_float2(1.f, 0.f);
        for (int r = 0; r < 15; r++) {
            #pragma unroll
            for (int mm = 0; mm < 4; mm++) {
                if (mm < cnt) {
                    float2 v = sP1[(m0 + mm) * N + off + r];
                    pacc[mm].x += v.x * wv.x - v.y * wv.y;
                    pacc[mm].y += v.x * wv.y + v.y * wv.x;
                }
            }
            float nx = wv.x * wg.x - wv.y * wg.y;
            wv.y = wv.x * wg.y + wv.y * wg.x;
            wv.x = nx;
        }
        #pragma unroll
        for (int mm = 0; mm < 4; mm++) {
            if (mm < cnt) sP1[(m0 + mm) * N + g] = pacc[mm];
        }
    }
    __syncthreads();

    // ---- beta synthesis, a-outer scalars, mirror rows ----
    if (g < N) {
        float bx = sP1[g].x;
        float* ob = act + ((long long)bo * N + j) * (N * N);
        for (int ii = 0; ii < 2; ii++) {
            int a = wave * 2 + ii;            // a in [0,7]
            float se_c = 0.f, se_s = 0.f, so_c = 0.f, so_s = 0.f;
            int t0 = 0;
            #pragma unroll
            for (int m = 1; m < ROWS; m++) {
                t0 += a; if (t0 >= N) t0 -= N;
                float2 w0 = sW[t0];
                float2 v = sP1[m * N + g];
                if (m & 1) { so_c += v.x * w0.x; so_s += v.y * w0.y; }
                else       { se_c += v.x * w0.x; se_s += v.y * w0.y; }
            }
            float ep_ = se_c + se_s, em = se_c - se_s;
            float op_ = so_c + so_s, om = so_c - so_s;
            ob[a * N + g]        = fmaxf(bx + 2.f * (ep_ + op_), 0.f);
            ob[(a + 15) * N + g] = fmaxf(bx + 2.f * (ep_ - op_), 0.f);
            if (a != 0) {
                ob[(15 - a) * N + g] = fmaxf(bx + 2.f * (em - om), 0.f);
                ob[(30 - a) * N + g] = fmaxf(bx + 2.f * (em + om), 0.f);
            }
        }
    }
}

// ---------------- R21: grid-parallel SO3 integrate --------------------------
__global__ void integrate_kernel(const float* __restrict__ act,
                                 const float* __restrict__ wq,
                                 float* __restrict__ feat)
{
    int e = blockIdx.x;
    int lane = threadIdx.x;                   // 64
    const float* base = act + (size_t)e * 216;
    float acc = 0.f;
    for (int i = lane; i < 216; i += 64)
        acc += wq[104 + i / 36] * base[i];
    for (int off = 32; off; off >>= 1) acc += __shfl_down(acc, off);
    if (lane == 0) feat[e] = acc * (1.f / 36.f);
}

// ---------------- BN-MLP head (single block, integrate pre-done) ------------
__global__ void head_kernel(const float* __restrict__ featg,
    const float* __restrict__ g1, const float* __restrict__ be1,
    const float* __restrict__ w1, const float* __restrict__ b1,
    const float* __restrict__ g2, const float* __restrict__ be2,
    const float* __restrict__ w2, const float* __restrict__ b2,
    const float* __restrict__ g3, const float* __restrict__ be3,
    const float* __restrict__ w3, const float* __restrict__ b3,
    float* __restrict__ out)
{
    __shared__ float feat[512];
    __shared__ float xn[512];
    __shared__ float h1[512];
    __shared__ float h2[256];
    int tid = threadIdx.x;
    for (int t = tid; t < 512; t += blockDim.x) feat[t] = featg[t];
    __syncthreads();
    for (int c = tid; c < 64; c += blockDim.x) {
        float mu = 0.f;
        for (int b = 0; b < 8; b++) mu += feat[b*64 + c];
        mu *= 0.125f;
        float var = 0.f;
        for (int b = 0; b < 8; b++) { float d = feat[b*64 + c] - mu; var += d*d; }
        var *= 0.125f;
        float is = rsqrtf(var + 1e-5f);
        for (int b = 0; b < 8; b++) xn[b*64 + c] = g1[c] * (feat[b*64 + c] - mu) * is + be1[c];
    }
    __syncthreads();
    for (int t = tid; t < 512; t += blockDim.x) {
        int b = t >> 6, o = t & 63;
        float acc = b1[o];
        for (int i = 0; i < 64; i++) acc += xn[b*64 + i] * w1[i*64 + o];
        h1[t] = fmaxf(acc, 0.f);
    }
    __syncthreads();
    for (int c = tid; c < 64; c += blockDim.x) {
        float mu = 0.f;
        for (int b = 0; b < 8; b++) mu += h1[b*64 + c];
        mu *= 0.125f;
        float var = 0.f;
        for (int b = 0; b < 8; b++) { float d = h1[b*64 + c] - mu; var += d*d; }
        var *= 0.125f;
        float is = rsqrtf(var + 1e-5f);
        for (int b = 0; b < 8; b++) xn[b*64 + c] = g2[c] * (h1[b*64 + c] - mu) * is + be2[c];
    }
    __syncthreads();
    for (int t = tid; t < 256; t += blockDim.x) {
        int b = t >> 5, o = t & 31;
        float acc = b2[o];
        for (int i = 0; i < 64; i++) acc += xn[b*64 + i] * w2[i*32 + o];
        h2[t] = fmaxf(acc, 0.f);
    }
    __syncthreads();
    for (int c = tid; c < 32; c += blockDim.x) {
        float mu = 0.f;
        for (int b = 0; b < 8; b++) mu += h2[b*32 + c];
        mu *= 0.125f;
        float var = 0.f;
        for (int b = 0; b < 8; b++) { float d = h2[b*32 + c] - mu; var += d*d; }
        var *= 0.125f;
        float is = rsqrtf(var + 1e-5f);
        for (int b = 0; b < 8; b++) xn[b*32 + c] = g3[c] * (h2[b*32 + c] - mu) * is + be3[c];
    }
    __syncthreads();
    for (int t = tid; t < 80; t += blockDim.x) {
        int b = t / 10, o = t % 10;
        float acc = b3[o];
        for (int i = 0; i < 32; i++) acc += xn[b*32 + i] * w3[i*10 + o];
        out[t] = acc;
    }
}

// ---------------------------------------------------------------------------

static inline int hmin(int a, int b) { return a < b ? a : b; }
static inline int hmax(int a, int b) { return a > b ? a : b; }
static inline int twoff(int N) { return N == 60 ? 0 : N == 30 ? 60 : N == 14 ? 90 : 104; }
static inline int wqoffb(int b) { return b == 30 ? 0 : b == 15 ? 60 : b == 7 ? 90 : 104; }

extern "C" void kernel_launch(void* const* d_in, const int* in_sizes, int n_in,
                              void* d_out, int out_size, void* d_ws, size_t ws_size,
                              hipStream_t stream)
{
    (void)in_sizes; (void)n_in; (void)out_size;
    const double PI = 3.14159265358979323846;
    struct LD { int kind, b_in, b_out, Ci, Co; double bg; };
    const LD LAY[7] = {
        {0, 30, 30,  1,  8, PI/16},
        {1, 30, 15,  8, 16, PI/16},
        {1, 15, 15, 16, 16, PI/8},
        {1, 15,  7, 16, 24, PI/8},
        {1,  7,  7, 24, 24, PI/4},
        {1,  7,  3, 24, 32, PI/4},
        {1,  3,  3, 32, 64, PI/2},
    };

    float* ws = (float*)d_ws;
    size_t off = 0;
    auto alloc = [&](size_t n) -> size_t { size_t o = off; off += (n + 63) & ~(size_t)63; return o; };
    size_t oA    = alloc(13400000);   // Y buffer; +oB span = layer-0 G buffer
    size_t oB    = alloc(8200000);    // input spectrum / z split-K partials
    size_t oAct1 = alloc(13824000);
    size_t oAct2 = alloc(3456000);
    size_t oXH   = alloc(1200000);
    size_t oZ    = alloc(4800000);
    size_t oWQ   = alloc(128);
    size_t oTW   = alloc(256);
    size_t oFeat = alloc(512);
    size_t oDin[7], oDout[7], oDg[7];
    for (int i = 0; i < 7; i++) {
        const LD& L = LAY[i];
        long long S = SF(L.b_out);
        bool reuse = (i == 2 || i == 4 || i == 6);
        if (reuse) {
            oDin[i]  = oDout[i-1];
            oDout[i] = oDout[i-1];
        } else {
            size_t din_sz = (L.kind == 0) ? (size_t)(2*L.b_in) * L.b_out * L.b_out
                                          : (size_t)(2*L.b_in) * S;
            oDin[i]  = alloc(din_sz);
            oDout[i] = alloc((size_t)(2*L.b_out) * S);
        }
        oDg[i]   = alloc((size_t)S);
    }
    if ((off + 64) * sizeof(float) > ws_size) return;

    float2* TW = (float2*)(ws + oTW);
    float*  WQ = ws + oWQ;

    setup_kernel<<<1, 128, 0, stream>>>(TW, WQ);

    WigCfg cfg;
    WigJmCfg jcfg;
    int ns = 0, totBlk = 0, njs = 0, jTot = 0;
    auto addSeg = [&](int nblk, size_t o, int b_out, int colmode, int jmaj, int nb,
                      double b0, double bs) {
        cfg.nblk[ns] = nblk; cfg.off[ns] = (int)o; cfg.b_out[ns] = b_out;
        cfg.colmode[ns] = colmode; cfg.jmaj[ns] = jmaj; cfg.nb[ns] = nb;
        cfg.beta0[ns] = b0; cfg.bstep[ns] = bs;
        ns++; totBlk += nblk;
    };
    auto addJmSeg = [&](size_t o, int b_out, int colmode, int nb,
                        double b0, double bs) {
        int rc = 256 / nb;
        int blocks = 0;
        for (int l = 0; l < b_out; l++) {
            int dim = 2*l + 1;
            int etot = colmode ? dim : dim * dim;
            blocks += (etot + rc - 1) / rc;
        }
        jcfg.nblk[njs] = blocks; jcfg.off[njs] = (int)o; jcfg.b_out[njs] = b_out;
        jcfg.colmode[njs] = colmode; jcfg.nb[njs] = nb; jcfg.rc[njs] = rc;
        jcfg.beta0[njs] = b0; jcfg.bstep[njs] = bs;
        njs++; jTot += blocks;
    };
    for (int i = 0; i < 7; i++) {
        const LD& L = LAY[i];
        bool reuse = (i == 2 || i == 4 || i == 6);
        if (!reuse) {
            // din: j-minor [e][nb]
            addJmSeg(oDin[i], L.b_out, (L.kind == 0) ? 1 : 0, 2*L.b_in,
                     PI/(4.0*L.b_in), PI/(2.0*L.b_in));
            if (i == 0) {
                // layer-0 dout j-minor [e][60] for g_build60
                addJmSeg(oDout[0], L.b_out, 0, 2*L.b_out,
                         PI/(4.0*L.b_out), PI/(2.0*L.b_out));
            } else {
                addSeg(2*L.b_out * L.b_out, oDout[i], L.b_out, 0, 0,
                       2*L.b_out, PI/(4.0*L.b_out), PI/(2.0*L.b_out));
            }
        }
        addSeg(L.b_out, oDg[i], L.b_out, 0, 0, 1, L.bg, 0.0);
    }
    cfg.nseg = ns;
    jcfg.nseg = njs;
    wigner_all_kernel<<<totBlk, 128, 0, stream>>>(ws, cfg);
    wigner_jm_kernel<<<jTot, 256, 0, stream>>>(ws, jcfg);

    const int Bt = 8;
    const float* cur = (const float*)d_in[0];
    float* actbuf[2] = { ws + oAct1, ws + oAct2 };

    for (int i = 0; i < 7; i++) {
        const LD& L = LAY[i];
        int Nin = 2*L.b_in, Nout = 2*L.b_out, M = 2*L.b_out - 1;
        float2* Bb = (float2*)(ws + oB);
        float2* XH = (float2*)(ws + oXH);
        float2* Z  = (float2*)(ws + oZ);
        const float2* TWin  = TW + twoff(Nin);
        const float2* TWout = TW + twoff(Nout);
        const float*  wql   = WQ + wqoffb(L.b_in);
        const float*  kw    = (const float*)d_in[1 + i];
        float* actOut = actbuf[i & 1];
        bool reuse = (i == 2 || i == 4 || i == 6);
        int eMul = reuse ? 1 : Nin;
        int jMul = reuse ? (int)SF(L.b_out) : 1;

        if (L.kind == 0) {
            int R = Bt * L.Ci * Nin;
            int RPB = hmin(R, hmax(1, 2 * DFT_LDS / Nin));
            dft_r_kernel<<<(R + RPB - 1) / RPB, 256, 0, stream>>>(
                cur, Bb, TWin, R, Nin, L.b_out, RPB);
            int gx = (Bt * L.Ci * L.b_out + 255) / 256;
            xh_s2_kernel<<<dim3(gx, L.b_out), 256, 0, stream>>>(
                Bb, ws + oDin[i], wql, XH, Bt, L.Ci, Nin, L.b_out, eMul, jMul);
            int gz = (Bt * L.Co * L.b_out * M + 255) / 256;
            z_s2_direct<<<dim3(gz, L.b_out), 256, 0, stream>>>(
                XH, kw, ws + oDg[i], Z, Bt, L.Ci, L.Co, L.b_out);
        } else {
            // fused 2-pass input FFT (gamma n>=0 + alpha dual +-n), radix-2
            int Rs = Bt * L.Ci * Nin;     // slabs of [alpha=Nin][gamma=Nin]
            int SPB = (Nin >= 60) ? 1 : (Nin >= 30) ? 2 : (Nin >= 14) ? 8 : 16;
            size_t lds = (size_t)Nin * sizeof(float2)
                       + (size_t)SPB * ((size_t)Nin * Nin * sizeof(float)
                                        + (size_t)Nin * L.b_out * sizeof(float2));
            fft2_kernel<<<(Rs + SPB - 1) / SPB, 256, lds, stream>>>(
                cur, Bb, TWin, Rs, Nin, L.b_out, SPB);
            int gx = (Bt * L.Ci * L.b_out * M + 255) / 256;
            xh_so3_kernel<<<dim3(gx, L.b_out), 256, 0, stream>>>(
                Bb, ws + oDin[i], wql, XH, Bt, L.Ci, Nin, L.b_out, eMul, jMul);
            float2* Yb = (float2*)(ws + oA);
            int ty = L.Ci * M * L.Co * M;
            y_so3_direct<<<dim3((ty + 255) / 256, L.b_out), 256, 0, stream>>>(
                kw, ws + oDg[i], Yb, L.Ci, L.Co, L.b_out);
            // R23: split-K z-GEMM; partials in the dead oB buffer.
            const int KS = 4;
            long long partF2 = (long long)Bt * L.Co * SF(L.b_out);
            float2* Zp = (float2*)(ws + oB);
            int ntiles = (L.Co * M + 63) / 64;
            z_so3_gemm<<<dim3(ntiles, Bt * KS, L.b_out), 256, 0, stream>>>(
                XH, Yb, Z, Zp, Bt, L.Ci, L.Co, L.b_out, KS, partF2);
            int rb = (int)((partF2 + 255) / 256);
            z_reduce<<<rb, 256, 0, stream>>>(Z, Zp, partF2, partF2, KS);
        }

        int planes = Bt * L.Co * Nout;
        if (Nout == 60) {
            // R24: G-build (j-batched, coalesced) + phases 2-4 kernel.
            float2* Gb = (float2*)(ws + oA);
            g_build60<<<dim3(Bt * L.Co, 225), 512, 0, stream>>>(
                Z, ws + oDout[i], Gb);
            synth60b_kernel<<<planes, 256, 0, stream>>>(Gb, TWout, actOut, planes);
        } else if (Nout == 30) {
            synth30_kernel<<<planes, 256, 0, stream>>>(Z, ws + oDout[i], TWout, actOut, planes);
        } else if (Nout == 14) {
            synth_t<14, 7,16,4, 64><<<(planes + 3) / 4,  64, 0, stream>>>(Z, ws + oDout[i], TWout, actOut, planes);
        } else {
            synth_t< 6, 3, 8,8, 64><<<(planes + 7) / 8,  64, 0, stream>>>(Z, ws + oDout[i], TWout, actOut, planes);
        }
        cur = actOut;
    }

    integrate_kernel<<<512, 64, 0, stream>>>(cur, WQ, ws + oFeat);

    head_kernel<<<1, 256, 0, stream>>>(
        ws + oFeat,
        (const float*)d_in[8],  (const float*)d_in[9],  (const float*)d_in[10], (const float*)d_in[11],
        (const float*)d_in[12], (const float*)d_in[13], (const float*)d_in[14], (const float*)d_in[15],
        (const float*)d_in[16], (const float*)d_in[17], (const float*)d_in[18], (const float*)d_in[19],
        (float*)d_out);
}